// Round 1
// baseline (4838.583 us; speedup 1.0000x reference)
//
#include <hip/hip_runtime.h>
#include <hip/hip_bf16.h>
#include <stdint.h>
#include <math.h>

#define S_LEN 2048
#define HIDDEN 2048
#define NHEAD 16
#define QLORA 768
#define KVLORA 512
#define QKNOPE 128
#define QKROPE 64
#define QKHEAD 192
#define VDIM 128
#define HIN 8
#define DIN 128
#define TOPKN 512
#define EPSF 1e-5f

static __device__ __forceinline__ float wave_reduce_sum(float v) {
    #pragma unroll
    for (int off = 32; off > 0; off >>= 1) v += __shfl_down(v, off);
    return v;
}
static __device__ __forceinline__ float wave_reduce_max(float v) {
    #pragma unroll
    for (int off = 32; off > 0; off >>= 1) v = fmaxf(v, __shfl_down(v, off));
    return v;
}

// ---------------- Generic f32 GEMM: C[M,N] = A[M,K] * B[N,K]^T ----------------
#define BM 64
#define BN 64
#define BKK 16
__global__ __launch_bounds__(256) void gemm_xt(const float* __restrict__ A,
                                               const float* __restrict__ B,
                                               float* __restrict__ C,
                                               int M, int N, int K) {
    __shared__ float As[BM][BKK + 1];
    __shared__ float Bs[BN][BKK + 1];
    int bm = blockIdx.y, bn = blockIdx.x;
    int tid = threadIdx.x;
    int tx = tid % 16, ty = tid / 16;
    int row0 = bm * BM, col0 = bn * BN;
    float acc[4][4] = {};
    for (int k0 = 0; k0 < K; k0 += BKK) {
        for (int i = tid; i < BM * BKK; i += 256) {
            int r = i / BKK, c = i % BKK;
            int gr = row0 + r;
            As[r][c] = (gr < M) ? A[(size_t)gr * K + (k0 + c)] : 0.f;
        }
        for (int i = tid; i < BN * BKK; i += 256) {
            int r = i / BKK, c = i % BKK;
            int gr = col0 + r;
            Bs[r][c] = (gr < N) ? B[(size_t)gr * K + (k0 + c)] : 0.f;
        }
        __syncthreads();
        #pragma unroll
        for (int kk = 0; kk < BKK; ++kk) {
            float a[4], b[4];
            #pragma unroll
            for (int i = 0; i < 4; ++i) a[i] = As[ty * 4 + i][kk];
            #pragma unroll
            for (int j = 0; j < 4; ++j) b[j] = Bs[tx * 4 + j][kk];
            #pragma unroll
            for (int i = 0; i < 4; ++i)
                #pragma unroll
                for (int j = 0; j < 4; ++j) acc[i][j] += a[i] * b[j];
        }
        __syncthreads();
    }
    for (int i = 0; i < 4; ++i) {
        int r = row0 + ty * 4 + i;
        if (r >= M) continue;
        for (int j = 0; j < 4; ++j) {
            int c = col0 + tx * 4 + j;
            if (c < N) C[(size_t)r * N + c] = acc[i][j];
        }
    }
}

// ---------------- RMSNorm rows (in-place safe) ----------------
__global__ __launch_bounds__(256) void rmsnorm_rows(const float* __restrict__ x,
                                                    const float* __restrict__ w,
                                                    float* __restrict__ y, int ncols) {
    int row = blockIdx.x, tid = threadIdx.x;
    const float* xr = x + (size_t)row * ncols;
    float ss = 0.f;
    for (int c = tid; c < ncols; c += 256) { float v = xr[c]; ss += v * v; }
    __shared__ float red[4];
    ss = wave_reduce_sum(ss);
    if ((tid & 63) == 0) red[tid >> 6] = ss;
    __syncthreads();
    float tot = red[0] + red[1] + red[2] + red[3];
    float inv = rsqrtf(tot / (float)ncols + EPSF);
    for (int c = tid; c < ncols; c += 256)
        y[(size_t)row * ncols + c] = xr[c] * inv * w[c];
}

// ---------------- RoPE on q (last 64 of each head's 192), in-place ----------------
__global__ __launch_bounds__(256) void rope_q(float* __restrict__ qbuf,
                                              const float* __restrict__ cosT,
                                              const float* __restrict__ sinT) {
    int s = blockIdx.x;
    for (int i = threadIdx.x; i < NHEAD * 32; i += 256) {
        int h = i >> 5, d = i & 31;
        float* base = qbuf + ((size_t)s * NHEAD + h) * QKHEAD + QKNOPE;
        float x1 = base[d], x2 = base[d + 32];
        float c1 = cosT[s * 64 + d],      s1 = sinT[s * 64 + d];
        float c2 = cosT[s * 64 + d + 32], s2 = sinT[s * 64 + d + 32];
        base[d]      = x1 * c1 - x2 * s1;
        base[d + 32] = x2 * c2 + x1 * s2;
    }
}

// ---------------- kv post: rmsnorm first 512 -> kvlat, rope last 64 -> krope ----------------
__global__ __launch_bounds__(256) void kv_post(const float* __restrict__ kv,
                                               const float* __restrict__ kvw,
                                               const float* __restrict__ cosT,
                                               const float* __restrict__ sinT,
                                               float* __restrict__ kvlat,
                                               float* __restrict__ krope) {
    int s = blockIdx.x, tid = threadIdx.x;
    const float* row = kv + (size_t)s * (KVLORA + QKROPE);
    float ss = 0.f;
    for (int c = tid; c < KVLORA; c += 256) { float v = row[c]; ss += v * v; }
    __shared__ float red[4];
    ss = wave_reduce_sum(ss);
    if ((tid & 63) == 0) red[tid >> 6] = ss;
    __syncthreads();
    float tot = red[0] + red[1] + red[2] + red[3];
    float inv = rsqrtf(tot / (float)KVLORA + EPSF);
    for (int c = tid; c < KVLORA; c += 256)
        kvlat[(size_t)s * KVLORA + c] = row[c] * inv * kvw[c];
    if (tid < 32) {
        int d = tid;
        float x1 = row[KVLORA + d], x2 = row[KVLORA + d + 32];
        float c1 = cosT[s * 64 + d],      s1 = sinT[s * 64 + d];
        float c2 = cosT[s * 64 + d + 32], s2 = sinT[s * 64 + d + 32];
        krope[s * 64 + d]      = x1 * c1 - x2 * s1;
        krope[s * 64 + d + 32] = x2 * c2 + x1 * s2;
    }
}

// ---------------- ik post: layer_norm(128) + rope first 64 ----------------
__global__ __launch_bounds__(128) void ik_post(const float* __restrict__ ikraw,
                                               const float* __restrict__ w,
                                               const float* __restrict__ b,
                                               const float* __restrict__ cosT,
                                               const float* __restrict__ sinT,
                                               float* __restrict__ ikbuf) {
    int s = blockIdx.x, tid = threadIdx.x;
    float x = ikraw[(size_t)s * DIN + tid];
    __shared__ float redA[2], redB[2], sy[DIN];
    float sm = wave_reduce_sum(x);
    if ((tid & 63) == 0) redA[tid >> 6] = sm;
    __syncthreads();
    float mean = (redA[0] + redA[1]) / (float)DIN;
    float dx = x - mean;
    float vs = wave_reduce_sum(dx * dx);
    if ((tid & 63) == 0) redB[tid >> 6] = vs;
    __syncthreads();
    float var = (redB[0] + redB[1]) / (float)DIN;
    sy[tid] = dx * rsqrtf(var + EPSF) * w[tid] + b[tid];
    __syncthreads();
    float* outr = ikbuf + (size_t)s * DIN;
    if (tid < 32) {
        int d = tid;
        float c1 = cosT[s * 64 + d],      s1 = sinT[s * 64 + d];
        float c2 = cosT[s * 64 + d + 32], s2 = sinT[s * 64 + d + 32];
        outr[d]      = sy[d] * c1 - sy[d + 32] * s1;
        outr[d + 32] = sy[d + 32] * c2 + sy[d] * s2;
    } else if (tid >= 64) {
        outr[tid] = sy[tid];
    }
}

// ---------------- cq: fold iw into roped iq; scale 1/32 = (8*128)^-1/2 ----------------
__global__ __launch_bounds__(128) void cq_kernel(const float* __restrict__ iqraw,
                                                 const float* __restrict__ iwbuf,
                                                 const float* __restrict__ cosT,
                                                 const float* __restrict__ sinT,
                                                 float* __restrict__ cqbuf) {
    int s = blockIdx.x, d = threadIdx.x;
    __shared__ float siw[HIN];
    if (d < HIN) siw[d] = iwbuf[(size_t)s * HIN + d];
    __syncthreads();
    float acc = 0.f;
    float c1 = 0.f, s1 = 0.f;
    if (d < 64) { c1 = cosT[s * 64 + d]; s1 = sinT[s * 64 + d]; }
    #pragma unroll
    for (int h = 0; h < HIN; ++h) {
        const float* base = iqraw + ((size_t)s * HIN + h) * DIN;
        float v;
        if (d < 32)       v = base[d] * c1 - base[d + 32] * s1;
        else if (d < 64)  v = base[d] * c1 + base[d - 32] * s1;
        else              v = base[d];
        acc += siw[h] * v;
    }
    cqbuf[(size_t)s * DIN + d] = acc * 0.03125f;
}

// ---------------- exact top-512 per row (rows q >= 512), radix select ----------------
__global__ __launch_bounds__(256) void topk_rows(const float* __restrict__ iscore,
                                                 int* __restrict__ topk) {
    int q = TOPKN + blockIdx.x;
    int n = q + 1;
    __shared__ uint32_t skey[S_LEN];
    __shared__ int hist[256];
    __shared__ uint32_t sp;
    __shared__ int sr, pos;
    int tid = threadIdx.x;
    const float* row = iscore + (size_t)q * S_LEN;
    for (int i = tid; i < n; i += 256) {
        uint32_t u = __float_as_uint(row[i]);
        skey[i] = (u & 0x80000000u) ? ~u : (u | 0x80000000u);
    }
    __syncthreads();
    uint32_t prefix = 0;
    int remk = TOPKN;
    for (int pass = 0; pass < 4; ++pass) {
        int shift = 24 - 8 * pass;
        uint32_t pmask = pass ? (0xFFFFFFFFu << (shift + 8)) : 0u;
        for (int i = tid; i < 256; i += 256) hist[i] = 0;
        __syncthreads();
        for (int i = tid; i < n; i += 256) {
            uint32_t u = skey[i];
            if ((u & pmask) == prefix) atomicAdd(&hist[(u >> shift) & 255], 1);
        }
        __syncthreads();
        if (tid == 0) {
            int cum = 0;
            for (int bkt = 255; bkt >= 0; --bkt) {
                int nc = cum + hist[bkt];
                if (nc >= remk) { sp = prefix | ((uint32_t)bkt << shift); sr = remk - cum; break; }
                cum = nc;
            }
        }
        __syncthreads();
        prefix = sp; remk = sr;
        __syncthreads();
    }
    if (tid == 0) pos = 0;
    __syncthreads();
    int* orow = topk + (size_t)q * TOPKN;
    for (int i = tid; i < n; i += 256) {
        if (skey[i] > prefix) { int p = atomicAdd(&pos, 1); orow[p] = i; }
    }
    __syncthreads();
    if (tid == 0) {
        int p = pos;
        for (int i = 0; i < n && remk > 0; ++i) {
            if (skey[i] == prefix) { orow[p++] = i; --remk; }
        }
    }
}

// ---------------- sparse masked attention, one block per (q, h) ----------------
__global__ __launch_bounds__(256) void attn_kernel(const float* __restrict__ qbuf,
                                                   const float* __restrict__ kvb,
                                                   const float* __restrict__ krope,
                                                   const int* __restrict__ topk,
                                                   float* __restrict__ attn_out) {
    int q = blockIdx.x, h = blockIdx.y;
    int tid = threadIdx.x;
    __shared__ float s_q[QKHEAD];
    __shared__ float s_sc[TOPKN];
    __shared__ float redm[4], reds[4], s_acc[256];
    for (int i = tid; i < QKHEAD; i += 256)
        s_q[i] = qbuf[((size_t)q * NHEAD + h) * QKHEAD + i];
    int L = (q < TOPKN) ? (q + 1) : TOPKN;
    const int* idxr = topk + (size_t)q * TOPKN;
    __syncthreads();
    const float scale = 0.07216878364870322f; // 192^-0.5
    for (int i = tid; i < L; i += 256) {
        int k = (q < TOPKN) ? i : idxr[i];
        const float* kn = kvb + ((size_t)k * NHEAD + h) * 256;
        const float* kr = krope + (size_t)k * 64;
        float acc = 0.f;
        #pragma unroll 8
        for (int d = 0; d < QKNOPE; ++d) acc += s_q[d] * kn[d];
        #pragma unroll 8
        for (int d = 0; d < QKROPE; ++d) acc += s_q[QKNOPE + d] * kr[d];
        s_sc[i] = acc * scale;
    }
    __syncthreads();
    float m = -1e30f;
    for (int i = tid; i < L; i += 256) m = fmaxf(m, s_sc[i]);
    m = wave_reduce_max(m);
    if ((tid & 63) == 0) redm[tid >> 6] = m;
    __syncthreads();
    m = fmaxf(fmaxf(redm[0], redm[1]), fmaxf(redm[2], redm[3]));
    float ssum = 0.f;
    for (int i = tid; i < L; i += 256) {
        float p = expf(s_sc[i] - m);
        s_sc[i] = p;
        ssum += p;
    }
    ssum = wave_reduce_sum(ssum);
    if ((tid & 63) == 0) reds[tid >> 6] = ssum;
    __syncthreads();
    float inv = 1.f / (reds[0] + reds[1] + reds[2] + reds[3]);
    int d = tid & 127, half = tid >> 7;
    float acc = 0.f;
    for (int i = half; i < L; i += 2) {
        int k = (q < TOPKN) ? i : idxr[i];
        acc += s_sc[i] * kvb[((size_t)k * NHEAD + h) * 256 + VDIM + d];
    }
    s_acc[tid] = acc;
    __syncthreads();
    if (tid < 128)
        attn_out[((size_t)q * NHEAD + h) * VDIM + d] = (s_acc[tid] + s_acc[tid + 128]) * inv;
}

extern "C" void kernel_launch(void* const* d_in, const int* in_sizes, int n_in,
                              void* d_out, int out_size, void* d_ws, size_t ws_size,
                              hipStream_t stream) {
    const float* hid          = (const float*)d_in[0];
    const float* cosT         = (const float*)d_in[1];
    const float* sinT         = (const float*)d_in[2];
    const float* wq_a         = (const float*)d_in[3];
    const float* q_a_norm_w   = (const float*)d_in[4];
    const float* wq_b         = (const float*)d_in[5];
    const float* wkv_a        = (const float*)d_in[6];
    const float* kv_a_norm_w  = (const float*)d_in[7];
    const float* wkv_b        = (const float*)d_in[8];
    const float* wo           = (const float*)d_in[9];
    const float* idx_wq_b     = (const float*)d_in[10];
    const float* idx_wk       = (const float*)d_in[11];
    const float* idx_k_norm_w = (const float*)d_in[12];
    const float* idx_k_norm_b = (const float*)d_in[13];
    const float* idx_weights_w= (const float*)d_in[14];
    float* out = (float*)d_out;

    char* ws = (char*)d_ws;
    size_t off = 0;
    auto alloc = [&](size_t nfloats) {
        float* p = (float*)(ws + off);
        off += nfloats * sizeof(float);
        off = (off + 255) & ~(size_t)255;
        return p;
    };
    float* q_lora   = alloc((size_t)S_LEN * QLORA);
    float* qbuf     = alloc((size_t)S_LEN * NHEAD * QKHEAD);
    float* kv       = alloc((size_t)S_LEN * (KVLORA + QKROPE));
    float* kvlat    = alloc((size_t)S_LEN * KVLORA);
    float* krope    = alloc((size_t)S_LEN * QKROPE);
    float* kvb      = alloc((size_t)S_LEN * NHEAD * (QKNOPE + VDIM));
    float* iqraw    = alloc((size_t)S_LEN * HIN * DIN);
    float* ikraw    = alloc((size_t)S_LEN * DIN);
    float* ikbuf    = alloc((size_t)S_LEN * DIN);
    float* iwbuf    = alloc((size_t)S_LEN * HIN);
    float* cqbuf    = alloc((size_t)S_LEN * DIN);
    float* iscore   = alloc((size_t)S_LEN * S_LEN);
    int*   topk     = (int*)alloc((size_t)S_LEN * TOPKN);
    float* attn_out = alloc((size_t)S_LEN * NHEAD * VDIM);
    (void)ws_size; (void)in_sizes; (void)n_in; (void)out_size;

    dim3 blk(256);
    auto grd = [](int M, int N) { return dim3((N + BN - 1) / BN, (M + BM - 1) / BM); };

    // q path
    gemm_xt<<<grd(S_LEN, QLORA), blk, 0, stream>>>(hid, wq_a, q_lora, S_LEN, QLORA, HIDDEN);
    rmsnorm_rows<<<S_LEN, 256, 0, stream>>>(q_lora, q_a_norm_w, q_lora, QLORA);
    gemm_xt<<<grd(S_LEN, NHEAD * QKHEAD), blk, 0, stream>>>(q_lora, wq_b, qbuf, S_LEN, NHEAD * QKHEAD, QLORA);
    rope_q<<<S_LEN, 256, 0, stream>>>(qbuf, cosT, sinT);
    // kv path
    gemm_xt<<<grd(S_LEN, KVLORA + QKROPE), blk, 0, stream>>>(hid, wkv_a, kv, S_LEN, KVLORA + QKROPE, HIDDEN);
    kv_post<<<S_LEN, 256, 0, stream>>>(kv, kv_a_norm_w, cosT, sinT, kvlat, krope);
    gemm_xt<<<grd(S_LEN, NHEAD * (QKNOPE + VDIM)), blk, 0, stream>>>(kvlat, wkv_b, kvb, S_LEN, NHEAD * (QKNOPE + VDIM), KVLORA);
    // indexer
    gemm_xt<<<grd(S_LEN, HIN * DIN), blk, 0, stream>>>(q_lora, idx_wq_b, iqraw, S_LEN, HIN * DIN, QLORA);
    gemm_xt<<<grd(S_LEN, DIN), blk, 0, stream>>>(hid, idx_wk, ikraw, S_LEN, DIN, HIDDEN);
    ik_post<<<S_LEN, 128, 0, stream>>>(ikraw, idx_k_norm_w, idx_k_norm_b, cosT, sinT, ikbuf);
    gemm_xt<<<grd(S_LEN, HIN), blk, 0, stream>>>(hid, idx_weights_w, iwbuf, S_LEN, HIN, HIDDEN);
    cq_kernel<<<S_LEN, 128, 0, stream>>>(iqraw, iwbuf, cosT, sinT, cqbuf);
    gemm_xt<<<grd(S_LEN, S_LEN), blk, 0, stream>>>(cqbuf, ikbuf, iscore, S_LEN, S_LEN, DIN);
    topk_rows<<<S_LEN - TOPKN, 256, 0, stream>>>(iscore, topk);
    // attention
    attn_kernel<<<dim3(S_LEN, NHEAD), 256, 0, stream>>>(qbuf, kvb, krope, topk, attn_out);
    // output projection
    gemm_xt<<<grd(S_LEN, HIDDEN), blk, 0, stream>>>(attn_out, wo, out, S_LEN, HIDDEN, NHEAD * VDIM);
}

// Round 2
// 3577.873 us; speedup vs baseline: 1.3524x; 1.3524x over previous
//
#include <hip/hip_runtime.h>
#include <hip/hip_bf16.h>
#include <stdint.h>
#include <math.h>

#define S_LEN 2048
#define HIDDEN 2048
#define NHEAD 16
#define QLORA 768
#define KVLORA 512
#define QKNOPE 128
#define QKROPE 64
#define QKHEAD 192
#define VDIM 128
#define HIN 8
#define DIN 128
#define TOPKN 512
#define EPSF 1e-5f
#define KVBROW (NHEAD * 256)   // 4096 bf16 per key row of kvb

typedef __bf16 bf16x8 __attribute__((ext_vector_type(8)));
typedef float  f32x4  __attribute__((ext_vector_type(4)));

static __device__ __forceinline__ float wave_reduce_sum(float v) {
    #pragma unroll
    for (int off = 32; off > 0; off >>= 1) v += __shfl_down(v, off);
    return v;
}
static __device__ __forceinline__ float wave_reduce_max(float v) {
    #pragma unroll
    for (int off = 32; off > 0; off >>= 1) v = fmaxf(v, __shfl_down(v, off));
    return v;
}

// ---------------- cast f32 -> bf16, 4 elems/thread ----------------
__global__ __launch_bounds__(256) void cast4(const float* __restrict__ in,
                                             __bf16* __restrict__ out, int n) {
    int i = (blockIdx.x * 256 + threadIdx.x) * 4;
    if (i < n) {
        f32x4 v = *(const f32x4*)(in + i);
        out[i + 0] = (__bf16)v[0];
        out[i + 1] = (__bf16)v[1];
        out[i + 2] = (__bf16)v[2];
        out[i + 3] = (__bf16)v[3];
    }
}

// ---------------- bf16 MFMA GEMM: C[M,N] = A[M,K]*B[N,K]^T ----------------
// Block tile 128x64, BK=32, 4 waves (2x2), wave tile 64x32.
// Requires M%128==0, N%64==0, K%32==0.
#define GBM 128
#define GBN 64
#define GBK 32
template <typename OutT>
__global__ __launch_bounds__(256) void gemm_bf16(const __bf16* __restrict__ A,
                                                 const __bf16* __restrict__ B,
                                                 OutT* __restrict__ C,
                                                 int M, int N, int K) {
    __shared__ __bf16 sA[GBM * GBK];
    __shared__ __bf16 sB[GBN * GBK];
    int tid = threadIdx.x;
    int lane = tid & 63, wid = tid >> 6;
    int quad = lane >> 4, l16 = lane & 15;
    int wm = wid >> 1, wn = wid & 1;
    int row0 = blockIdx.y * GBM, col0 = blockIdx.x * GBN;

    f32x4 acc[4][2] = {};
    int am = tid >> 1, ah = tid & 1;          // A staging: 2 threads/row, 16 elems each
    int bn = tid >> 2, bq = tid & 3;          // B staging: 4 threads/row, 8 elems each

    for (int k0 = 0; k0 < K; k0 += GBK) {
        const uint4* ga = (const uint4*)(A + (size_t)(row0 + am) * K + k0 + ah * 16);
        uint4* da = (uint4*)&sA[am * GBK + ah * 16];
        da[0] = ga[0];
        da[1] = ga[1];
        *(uint4*)&sB[bn * GBK + bq * 8] =
            *(const uint4*)(B + (size_t)(col0 + bn) * K + k0 + bq * 8);
        __syncthreads();

        bf16x8 af[4], bfr[2];
        #pragma unroll
        for (int mi = 0; mi < 4; ++mi)
            af[mi] = *(const bf16x8*)&sA[(wm * 64 + mi * 16 + l16) * GBK + quad * 8];
        #pragma unroll
        for (int ni = 0; ni < 2; ++ni)
            bfr[ni] = *(const bf16x8*)&sB[(wn * 32 + ni * 16 + l16) * GBK + quad * 8];
        #pragma unroll
        for (int mi = 0; mi < 4; ++mi)
            #pragma unroll
            for (int ni = 0; ni < 2; ++ni)
                acc[mi][ni] = __builtin_amdgcn_mfma_f32_16x16x32_bf16(
                    af[mi], bfr[ni], acc[mi][ni], 0, 0, 0);
        __syncthreads();
    }
    // C/D layout: col = lane&15, row = quad*4 + r  [verified m89/m91]
    #pragma unroll
    for (int mi = 0; mi < 4; ++mi) {
        #pragma unroll
        for (int ni = 0; ni < 2; ++ni) {
            #pragma unroll
            for (int r = 0; r < 4; ++r) {
                int row = row0 + wm * 64 + mi * 16 + quad * 4 + r;
                int col = col0 + wn * 32 + ni * 16 + l16;
                C[(size_t)row * N + col] = (OutT)acc[mi][ni][r];
            }
        }
    }
}

// ---------------- f32 GEMM: C[M,N] = A[M,K]*B[N,K]^T (bounds-checked) ----------------
#define BM 64
#define BN 64
#define BKK 16
__global__ __launch_bounds__(256) void gemm_xt(const float* __restrict__ A,
                                               const float* __restrict__ B,
                                               float* __restrict__ C,
                                               int M, int N, int K) {
    __shared__ float As2[BKK][BM + 4];
    __shared__ float Bs2[BKK][BN + 4];
    int bm = blockIdx.y, bn = blockIdx.x;
    int tid = threadIdx.x;
    int tx = tid % 16, ty = tid / 16;
    int row0 = bm * BM, col0 = bn * BN;
    float acc[4][4] = {};
    for (int k0 = 0; k0 < K; k0 += BKK) {
        for (int i = tid; i < BM * BKK; i += 256) {
            int r = i / BKK, c = i % BKK;
            int gr = row0 + r;
            As2[c][r] = (gr < M) ? A[(size_t)gr * K + (k0 + c)] : 0.f;
        }
        for (int i = tid; i < BN * BKK; i += 256) {
            int r = i / BKK, c = i % BKK;
            int gr = col0 + r;
            Bs2[c][r] = (gr < N) ? B[(size_t)gr * K + (k0 + c)] : 0.f;
        }
        __syncthreads();
        #pragma unroll
        for (int kk = 0; kk < BKK; ++kk) {
            f32x4 av = *(const f32x4*)&As2[kk][ty * 4];
            f32x4 bv = *(const f32x4*)&Bs2[kk][tx * 4];
            #pragma unroll
            for (int i = 0; i < 4; ++i)
                #pragma unroll
                for (int j = 0; j < 4; ++j) acc[i][j] += av[i] * bv[j];
        }
        __syncthreads();
    }
    for (int i = 0; i < 4; ++i) {
        int r = row0 + ty * 4 + i;
        if (r >= M) continue;
        for (int j = 0; j < 4; ++j) {
            int c = col0 + tx * 4 + j;
            if (c < N) C[(size_t)r * N + c] = acc[i][j];
        }
    }
}

// ---------------- RMSNorm rows (in-place safe) ----------------
__global__ __launch_bounds__(256) void rmsnorm_rows(const float* __restrict__ x,
                                                    const float* __restrict__ w,
                                                    float* __restrict__ y, int ncols) {
    int row = blockIdx.x, tid = threadIdx.x;
    const float* xr = x + (size_t)row * ncols;
    float ss = 0.f;
    for (int c = tid; c < ncols; c += 256) { float v = xr[c]; ss += v * v; }
    __shared__ float red[4];
    ss = wave_reduce_sum(ss);
    if ((tid & 63) == 0) red[tid >> 6] = ss;
    __syncthreads();
    float tot = red[0] + red[1] + red[2] + red[3];
    float inv = rsqrtf(tot / (float)ncols + EPSF);
    for (int c = tid; c < ncols; c += 256)
        y[(size_t)row * ncols + c] = xr[c] * inv * w[c];
}

// ---------------- RoPE on q (last 64 of each head's 192), in-place f32 ----------------
__global__ __launch_bounds__(256) void rope_q(float* __restrict__ qbuf,
                                              const float* __restrict__ cosT,
                                              const float* __restrict__ sinT) {
    int s = blockIdx.x;
    for (int i = threadIdx.x; i < NHEAD * 32; i += 256) {
        int h = i >> 5, d = i & 31;
        float* base = qbuf + ((size_t)s * NHEAD + h) * QKHEAD + QKNOPE;
        float x1 = base[d], x2 = base[d + 32];
        float c1 = cosT[s * 64 + d],      s1 = sinT[s * 64 + d];
        float c2 = cosT[s * 64 + d + 32], s2 = sinT[s * 64 + d + 32];
        base[d]      = x1 * c1 - x2 * s1;
        base[d + 32] = x2 * c2 + x1 * s2;
    }
}

// ---------------- kv post: rmsnorm first 512 -> kvlat_bf, rope last 64 -> krope_bf ---
__global__ __launch_bounds__(256) void kv_post(const float* __restrict__ kv,
                                               const float* __restrict__ kvw,
                                               const float* __restrict__ cosT,
                                               const float* __restrict__ sinT,
                                               __bf16* __restrict__ kvlat_bf,
                                               __bf16* __restrict__ krope_bf) {
    int s = blockIdx.x, tid = threadIdx.x;
    const float* row = kv + (size_t)s * (KVLORA + QKROPE);
    float ss = 0.f;
    for (int c = tid; c < KVLORA; c += 256) { float v = row[c]; ss += v * v; }
    __shared__ float red[4];
    ss = wave_reduce_sum(ss);
    if ((tid & 63) == 0) red[tid >> 6] = ss;
    __syncthreads();
    float tot = red[0] + red[1] + red[2] + red[3];
    float inv = rsqrtf(tot / (float)KVLORA + EPSF);
    for (int c = tid; c < KVLORA; c += 256)
        kvlat_bf[(size_t)s * KVLORA + c] = (__bf16)(row[c] * inv * kvw[c]);
    if (tid < 32) {
        int d = tid;
        float x1 = row[KVLORA + d], x2 = row[KVLORA + d + 32];
        float c1 = cosT[s * 64 + d],      s1 = sinT[s * 64 + d];
        float c2 = cosT[s * 64 + d + 32], s2 = sinT[s * 64 + d + 32];
        krope_bf[s * 64 + d]      = (__bf16)(x1 * c1 - x2 * s1);
        krope_bf[s * 64 + d + 32] = (__bf16)(x2 * c2 + x1 * s2);
    }
}

// ---------------- ik post: layer_norm(128) + rope first 64 (f32, indexer path) ------
__global__ __launch_bounds__(128) void ik_post(const float* __restrict__ ikraw,
                                               const float* __restrict__ w,
                                               const float* __restrict__ b,
                                               const float* __restrict__ cosT,
                                               const float* __restrict__ sinT,
                                               float* __restrict__ ikbuf) {
    int s = blockIdx.x, tid = threadIdx.x;
    float x = ikraw[(size_t)s * DIN + tid];
    __shared__ float redA[2], redB[2], sy[DIN];
    float sm = wave_reduce_sum(x);
    if ((tid & 63) == 0) redA[tid >> 6] = sm;
    __syncthreads();
    float mean = (redA[0] + redA[1]) / (float)DIN;
    float dx = x - mean;
    float vs = wave_reduce_sum(dx * dx);
    if ((tid & 63) == 0) redB[tid >> 6] = vs;
    __syncthreads();
    float var = (redB[0] + redB[1]) / (float)DIN;
    sy[tid] = dx * rsqrtf(var + EPSF) * w[tid] + b[tid];
    __syncthreads();
    float* outr = ikbuf + (size_t)s * DIN;
    if (tid < 32) {
        int d = tid;
        float c1 = cosT[s * 64 + d],      s1 = sinT[s * 64 + d];
        float c2 = cosT[s * 64 + d + 32], s2 = sinT[s * 64 + d + 32];
        outr[d]      = sy[d] * c1 - sy[d + 32] * s1;
        outr[d + 32] = sy[d + 32] * c2 + sy[d] * s2;
    } else if (tid >= 64) {
        outr[tid] = sy[tid];
    }
}

// ---------------- cq: fold iw into roped iq; scale 1/32 (f32, indexer path) ---------
__global__ __launch_bounds__(128) void cq_kernel(const float* __restrict__ iqraw,
                                                 const float* __restrict__ iwbuf,
                                                 const float* __restrict__ cosT,
                                                 const float* __restrict__ sinT,
                                                 float* __restrict__ cqbuf) {
    int s = blockIdx.x, d = threadIdx.x;
    __shared__ float siw[HIN];
    if (d < HIN) siw[d] = iwbuf[(size_t)s * HIN + d];
    __syncthreads();
    float acc = 0.f;
    float c1 = 0.f, s1 = 0.f;
    if (d < 64) { c1 = cosT[s * 64 + d]; s1 = sinT[s * 64 + d]; }
    #pragma unroll
    for (int h = 0; h < HIN; ++h) {
        const float* base = iqraw + ((size_t)s * HIN + h) * DIN;
        float v;
        if (d < 32)       v = base[d] * c1 - base[d + 32] * s1;
        else if (d < 64)  v = base[d] * c1 + base[d - 32] * s1;
        else              v = base[d];
        acc += siw[h] * v;
    }
    cqbuf[(size_t)s * DIN + d] = acc * 0.03125f;
}

// ---------------- exact top-512 per row (rows q >= 512), radix select ----------------
__global__ __launch_bounds__(256) void topk_rows(const float* __restrict__ iscore,
                                                 int* __restrict__ topk) {
    int q = TOPKN + blockIdx.x;
    int n = q + 1;
    __shared__ uint32_t skey[S_LEN];
    __shared__ int hist[256];
    __shared__ uint32_t sp;
    __shared__ int sr, pos;
    int tid = threadIdx.x;
    const float* row = iscore + (size_t)q * S_LEN;
    for (int i = tid; i < n; i += 256) {
        uint32_t u = __float_as_uint(row[i]);
        skey[i] = (u & 0x80000000u) ? ~u : (u | 0x80000000u);
    }
    __syncthreads();
    uint32_t prefix = 0;
    int remk = TOPKN;
    for (int pass = 0; pass < 4; ++pass) {
        int shift = 24 - 8 * pass;
        uint32_t pmask = pass ? (0xFFFFFFFFu << (shift + 8)) : 0u;
        for (int i = tid; i < 256; i += 256) hist[i] = 0;
        __syncthreads();
        for (int i = tid; i < n; i += 256) {
            uint32_t u = skey[i];
            if ((u & pmask) == prefix) atomicAdd(&hist[(u >> shift) & 255], 1);
        }
        __syncthreads();
        if (tid == 0) {
            int cum = 0;
            for (int bkt = 255; bkt >= 0; --bkt) {
                int nc = cum + hist[bkt];
                if (nc >= remk) { sp = prefix | ((uint32_t)bkt << shift); sr = remk - cum; break; }
                cum = nc;
            }
        }
        __syncthreads();
        prefix = sp; remk = sr;
        __syncthreads();
    }
    if (tid == 0) pos = 0;
    __syncthreads();
    int* orow = topk + (size_t)q * TOPKN;
    for (int i = tid; i < n; i += 256) {
        if (skey[i] > prefix) { int p = atomicAdd(&pos, 1); orow[p] = i; }
    }
    __syncthreads();
    if (tid == 0) {
        int p = pos;
        for (int i = 0; i < n && remk > 0; ++i) {
            if (skey[i] == prefix) { orow[p++] = i; --remk; }
        }
    }
}

// 8-elem bf16 dot with f32 q from LDS
static __device__ __forceinline__ void bfdot8(uint4 u, const float* q, float& acc) {
    acc += __uint_as_float(u.x << 16)           * q[0];
    acc += __uint_as_float(u.x & 0xffff0000u)   * q[1];
    acc += __uint_as_float(u.y << 16)           * q[2];
    acc += __uint_as_float(u.y & 0xffff0000u)   * q[3];
    acc += __uint_as_float(u.z << 16)           * q[4];
    acc += __uint_as_float(u.z & 0xffff0000u)   * q[5];
    acc += __uint_as_float(u.w << 16)           * q[6];
    acc += __uint_as_float(u.w & 0xffff0000u)   * q[7];
}

// ---------------- sparse masked attention, one block per (q, h); bf16 K/V ------------
__global__ __launch_bounds__(256) void attn_kernel(const float* __restrict__ qbuf,
                                                   const __bf16* __restrict__ kvb,
                                                   const __bf16* __restrict__ krope,
                                                   const int* __restrict__ topk,
                                                   __bf16* __restrict__ attn_out) {
    int q = blockIdx.x, h = blockIdx.y;
    int tid = threadIdx.x;
    __shared__ float s_q[QKHEAD];
    __shared__ float s_sc[TOPKN];
    __shared__ float redm[4], reds[4];
    __shared__ float s_va[256], s_vb[256];
    if (tid < QKHEAD) s_q[tid] = qbuf[((size_t)q * NHEAD + h) * QKHEAD + tid];
    int L = (q < TOPKN) ? (q + 1) : TOPKN;
    const int* idxr = topk + (size_t)q * TOPKN;
    __syncthreads();
    const float scale = 0.07216878364870322f; // 192^-0.5
    for (int i = tid; i < L; i += 256) {
        int k = (q < TOPKN) ? i : idxr[i];
        const uint4* kn = (const uint4*)(kvb + (size_t)k * KVBROW + h * 256);
        const uint4* kr = (const uint4*)(krope + (size_t)k * 64);
        float acc = 0.f;
        #pragma unroll
        for (int c = 0; c < 16; ++c) bfdot8(kn[c], &s_q[c * 8], acc);
        #pragma unroll
        for (int c = 0; c < 8; ++c) bfdot8(kr[c], &s_q[128 + c * 8], acc);
        s_sc[i] = acc * scale;
    }
    __syncthreads();
    float m = -1e30f;
    for (int i = tid; i < L; i += 256) m = fmaxf(m, s_sc[i]);
    m = wave_reduce_max(m);
    if ((tid & 63) == 0) redm[tid >> 6] = m;
    __syncthreads();
    m = fmaxf(fmaxf(redm[0], redm[1]), fmaxf(redm[2], redm[3]));
    float ssum = 0.f;
    for (int i = tid; i < L; i += 256) {
        float p = expf(s_sc[i] - m);
        s_sc[i] = p;
        ssum += p;
    }
    ssum = wave_reduce_sum(ssum);
    if ((tid & 63) == 0) reds[tid >> 6] = ssum;
    __syncthreads();
    float inv = 1.f / (reds[0] + reds[1] + reds[2] + reds[3]);
    // V accumulation: lane covers 2 consecutive dims (coalesced uint loads)
    int dp = tid & 63, grp = tid >> 6;
    float a0 = 0.f, a1 = 0.f;
    for (int i = grp; i < L; i += 4) {
        int k = (q < TOPKN) ? i : idxr[i];
        uint32_t u = *(const uint32_t*)(kvb + (size_t)k * KVBROW + h * 256 + 128 + 2 * dp);
        float p = s_sc[i];
        a0 += p * __uint_as_float(u << 16);
        a1 += p * __uint_as_float(u & 0xffff0000u);
    }
    s_va[tid] = a0; s_vb[tid] = a1;
    __syncthreads();
    if (tid < 64) {
        float x0 = s_va[tid] + s_va[tid + 64] + s_va[tid + 128] + s_va[tid + 192];
        float x1 = s_vb[tid] + s_vb[tid + 64] + s_vb[tid + 128] + s_vb[tid + 192];
        __bf16* o = attn_out + (size_t)q * (NHEAD * VDIM) + h * VDIM + 2 * dp;
        o[0] = (__bf16)(x0 * inv);
        o[1] = (__bf16)(x1 * inv);
    }
}

extern "C" void kernel_launch(void* const* d_in, const int* in_sizes, int n_in,
                              void* d_out, int out_size, void* d_ws, size_t ws_size,
                              hipStream_t stream) {
    const float* hid          = (const float*)d_in[0];
    const float* cosT         = (const float*)d_in[1];
    const float* sinT         = (const float*)d_in[2];
    const float* wq_a         = (const float*)d_in[3];
    const float* q_a_norm_w   = (const float*)d_in[4];
    const float* wq_b         = (const float*)d_in[5];
    const float* wkv_a        = (const float*)d_in[6];
    const float* kv_a_norm_w  = (const float*)d_in[7];
    const float* wkv_b        = (const float*)d_in[8];
    const float* wo           = (const float*)d_in[9];
    const float* idx_wq_b     = (const float*)d_in[10];
    const float* idx_wk       = (const float*)d_in[11];
    const float* idx_k_norm_w = (const float*)d_in[12];
    const float* idx_k_norm_b = (const float*)d_in[13];
    const float* idx_weights_w= (const float*)d_in[14];
    float* out = (float*)d_out;

    char* ws = (char*)d_ws;
    size_t off = 0;
    auto alloc = [&](size_t nbytes) {
        void* p = (void*)(ws + off);
        off += nbytes;
        off = (off + 255) & ~(size_t)255;
        return p;
    };
    float*  q_lora     = (float*) alloc((size_t)S_LEN * QLORA * 4);
    float*  qbuf       = (float*) alloc((size_t)S_LEN * NHEAD * QKHEAD * 4);
    float*  kv         = (float*) alloc((size_t)S_LEN * (KVLORA + QKROPE) * 4);
    __bf16* kvlat_bf   = (__bf16*)alloc((size_t)S_LEN * KVLORA * 2);
    __bf16* krope_bf   = (__bf16*)alloc((size_t)S_LEN * QKROPE * 2);
    __bf16* kvb_bf     = (__bf16*)alloc((size_t)S_LEN * KVBROW * 2);
    float*  iqraw      = (float*) alloc((size_t)S_LEN * HIN * DIN * 4);
    float*  ikraw      = (float*) alloc((size_t)S_LEN * DIN * 4);
    float*  ikbuf      = (float*) alloc((size_t)S_LEN * DIN * 4);
    float*  iwbuf      = (float*) alloc((size_t)S_LEN * HIN * 4);
    float*  cqbuf      = (float*) alloc((size_t)S_LEN * DIN * 4);
    float*  iscore     = (float*) alloc((size_t)S_LEN * S_LEN * 4);
    int*    topk       = (int*)   alloc((size_t)S_LEN * TOPKN * 4);
    __bf16* attn_o_bf  = (__bf16*)alloc((size_t)S_LEN * NHEAD * VDIM * 2);
    __bf16* hid_bf     = (__bf16*)alloc((size_t)S_LEN * HIDDEN * 2);
    __bf16* q_lora_bf  = (__bf16*)alloc((size_t)S_LEN * QLORA * 2);
    __bf16* wq_b_bf    = (__bf16*)alloc((size_t)(NHEAD * QKHEAD) * QLORA * 2);
    __bf16* wkv_a_bf   = (__bf16*)alloc((size_t)(KVLORA + QKROPE) * HIDDEN * 2);
    __bf16* wkv_b_bf   = (__bf16*)alloc((size_t)(NHEAD * 256) * KVLORA * 2);
    __bf16* wo_bf      = (__bf16*)alloc((size_t)HIDDEN * (NHEAD * VDIM) * 2);
    (void)ws_size; (void)in_sizes; (void)n_in; (void)out_size;

    dim3 blk(256);
    auto grd  = [](int M, int N) { return dim3((N + BN - 1) / BN, (M + BM - 1) / BM); };
    auto grdb = [](int M, int N) { return dim3(N / GBN, M / GBM); };
    auto cst  = [&](const float* src, __bf16* dst, int n) {
        cast4<<<(n / 4 + 255) / 256, blk, 0, stream>>>(src, dst, n);
    };

    // weight/input casts (independent)
    cst(hid,   hid_bf,   S_LEN * HIDDEN);
    cst(wq_b,  wq_b_bf,  NHEAD * QKHEAD * QLORA);
    cst(wkv_a, wkv_a_bf, (KVLORA + QKROPE) * HIDDEN);
    cst(wkv_b, wkv_b_bf, NHEAD * 256 * KVLORA);
    cst(wo,    wo_bf,    HIDDEN * NHEAD * VDIM);

    // q path (q_lora stays f32: feeds the indexer)
    gemm_xt<<<grd(S_LEN, QLORA), blk, 0, stream>>>(hid, wq_a, q_lora, S_LEN, QLORA, HIDDEN);
    rmsnorm_rows<<<S_LEN, 256, 0, stream>>>(q_lora, q_a_norm_w, q_lora, QLORA);
    cst(q_lora, q_lora_bf, S_LEN * QLORA);
    gemm_bf16<float><<<grdb(S_LEN, NHEAD * QKHEAD), blk, 0, stream>>>(
        q_lora_bf, wq_b_bf, qbuf, S_LEN, NHEAD * QKHEAD, QLORA);
    rope_q<<<S_LEN, 256, 0, stream>>>(qbuf, cosT, sinT);
    // kv path
    gemm_bf16<float><<<grdb(S_LEN, KVLORA + QKROPE), blk, 0, stream>>>(
        hid_bf, wkv_a_bf, kv, S_LEN, KVLORA + QKROPE, HIDDEN);
    kv_post<<<S_LEN, 256, 0, stream>>>(kv, kv_a_norm_w, cosT, sinT, kvlat_bf, krope_bf);
    gemm_bf16<__bf16><<<grdb(S_LEN, NHEAD * 256), blk, 0, stream>>>(
        kvlat_bf, wkv_b_bf, kvb_bf, S_LEN, NHEAD * 256, KVLORA);
    // indexer (all f32 — top-k set membership is precision-sensitive)
    gemm_xt<<<grd(S_LEN, HIN * DIN), blk, 0, stream>>>(q_lora, idx_wq_b, iqraw, S_LEN, HIN * DIN, QLORA);
    gemm_xt<<<grd(S_LEN, DIN), blk, 0, stream>>>(hid, idx_wk, ikraw, S_LEN, DIN, HIDDEN);
    ik_post<<<S_LEN, 128, 0, stream>>>(ikraw, idx_k_norm_w, idx_k_norm_b, cosT, sinT, ikbuf);
    gemm_xt<<<grd(S_LEN, HIN), blk, 0, stream>>>(hid, idx_weights_w, iwbuf, S_LEN, HIN, HIDDEN);
    cq_kernel<<<S_LEN, 128, 0, stream>>>(iqraw, iwbuf, cosT, sinT, cqbuf);
    gemm_xt<<<grd(S_LEN, S_LEN), blk, 0, stream>>>(cqbuf, ikbuf, iscore, S_LEN, S_LEN, DIN);
    topk_rows<<<S_LEN - TOPKN, 256, 0, stream>>>(iscore, topk);
    // attention (bf16 K/V gather)
    attn_kernel<<<dim3(S_LEN, NHEAD), 256, 0, stream>>>(qbuf, kvb_bf, krope_bf, topk, attn_o_bf);
    // output projection
    gemm_bf16<float><<<grdb(S_LEN, HIDDEN), blk, 0, stream>>>(
        attn_o_bf, wo_bf, out, S_LEN, HIDDEN, NHEAD * VDIM);
}

// Round 3
// 1698.825 us; speedup vs baseline: 2.8482x; 2.1061x over previous
//
#include <hip/hip_runtime.h>
#include <hip/hip_bf16.h>
#include <stdint.h>
#include <math.h>

#define S_LEN 2048
#define HIDDEN 2048
#define NHEAD 16
#define QLORA 768
#define KVLORA 512
#define QKNOPE 128
#define QKROPE 64
#define QKHEAD 192
#define VDIM 128
#define HIN 8
#define DIN 128
#define TOPKN 512
#define EPSF 1e-5f
#define DLAT 576           // 512 latent + 64 rope
#define SCALE_ATT 0.07216878364870322f  // 192^-0.5

typedef __bf16 bf16x8 __attribute__((ext_vector_type(8)));
typedef float  f32x4  __attribute__((ext_vector_type(4)));

static __device__ __forceinline__ float wave_reduce_sum(float v) {
    #pragma unroll
    for (int off = 32; off > 0; off >>= 1) v += __shfl_down(v, off);
    return v;
}

// ---------------- cast f32 -> bf16, 4 elems/thread ----------------
__global__ __launch_bounds__(256) void cast4(const float* __restrict__ in,
                                             __bf16* __restrict__ out, int n) {
    int i = (blockIdx.x * 256 + threadIdx.x) * 4;
    if (i < n) {
        f32x4 v = *(const f32x4*)(in + i);
        out[i + 0] = (__bf16)v[0];
        out[i + 1] = (__bf16)v[1];
        out[i + 2] = (__bf16)v[2];
        out[i + 3] = (__bf16)v[3];
    }
}

// wknt[h][c][d] = wkv_b[(h*256+d)*512 + c]  (per-head K-nope weight, transposed, bf16)
__global__ __launch_bounds__(256) void transpose_wkn(const float* __restrict__ wkv_b,
                                                     __bf16* __restrict__ wknt) {
    int t = blockIdx.x * 256 + threadIdx.x;       // 16*512*128 total
    int c = t & 511, d = (t >> 9) & 127, h = t >> 16;
    wknt[(size_t)h * 65536 + c * 128 + d] =
        (__bf16)wkv_b[((size_t)(h * 256 + d)) * 512 + c];
}

// ---------------- bf16 MFMA GEMM (strided, batched): C = A*B^T ----------------
// Block tile 128x64, BK=32, 4 waves. M%128==0, N%64==0, K%32==0.
#define GBM 128
#define GBN 64
#define GBK 32
template <typename OutT>
__global__ __launch_bounds__(256) void gemm_s(const __bf16* __restrict__ A,
                                              const __bf16* __restrict__ B,
                                              OutT* __restrict__ C,
                                              int M, int N, int K,
                                              int lda, int ldb, int ldc,
                                              long sA, long sB, long sC) {
    A += (size_t)blockIdx.z * sA;
    B += (size_t)blockIdx.z * sB;
    C += (size_t)blockIdx.z * sC;
    __shared__ __bf16 sAs[GBM * GBK];
    __shared__ __bf16 sBs[GBN * GBK];
    int tid = threadIdx.x;
    int lane = tid & 63, wid = tid >> 6;
    int quad = lane >> 4, l16 = lane & 15;
    int wm = wid >> 1, wn = wid & 1;
    int row0 = blockIdx.y * GBM, col0 = blockIdx.x * GBN;

    f32x4 acc[4][2] = {};
    int am = tid >> 1, ah = tid & 1;
    int bn = tid >> 2, bq = tid & 3;

    for (int k0 = 0; k0 < K; k0 += GBK) {
        const uint4* ga = (const uint4*)(A + (size_t)(row0 + am) * lda + k0 + ah * 16);
        uint4* da = (uint4*)&sAs[am * GBK + ah * 16];
        da[0] = ga[0];
        da[1] = ga[1];
        *(uint4*)&sBs[bn * GBK + bq * 8] =
            *(const uint4*)(B + (size_t)(col0 + bn) * ldb + k0 + bq * 8);
        __syncthreads();
        bf16x8 af[4], bfr[2];
        #pragma unroll
        for (int mi = 0; mi < 4; ++mi)
            af[mi] = *(const bf16x8*)&sAs[(wm * 64 + mi * 16 + l16) * GBK + quad * 8];
        #pragma unroll
        for (int ni = 0; ni < 2; ++ni)
            bfr[ni] = *(const bf16x8*)&sBs[(wn * 32 + ni * 16 + l16) * GBK + quad * 8];
        #pragma unroll
        for (int mi = 0; mi < 4; ++mi)
            #pragma unroll
            for (int ni = 0; ni < 2; ++ni)
                acc[mi][ni] = __builtin_amdgcn_mfma_f32_16x16x32_bf16(
                    af[mi], bfr[ni], acc[mi][ni], 0, 0, 0);
        __syncthreads();
    }
    #pragma unroll
    for (int mi = 0; mi < 4; ++mi)
        #pragma unroll
        for (int ni = 0; ni < 2; ++ni)
            #pragma unroll
            for (int r = 0; r < 4; ++r) {
                int row = row0 + wm * 64 + mi * 16 + quad * 4 + r;
                int col = col0 + wn * 32 + ni * 16 + l16;
                C[(size_t)row * ldc + col] = (OutT)acc[mi][ni][r];
            }
}

// ---------------- f32 GEMM: C[M,N] = A[M,K]*B[N,K]^T (bounds-checked) ----------------
#define BM 64
#define BN 64
#define BKK 16
__global__ __launch_bounds__(256) void gemm_xt(const float* __restrict__ A,
                                               const float* __restrict__ B,
                                               float* __restrict__ C,
                                               int M, int N, int K) {
    __shared__ float As2[BKK][BM + 4];
    __shared__ float Bs2[BKK][BN + 4];
    int bm = blockIdx.y, bn = blockIdx.x;
    int tid = threadIdx.x;
    int tx = tid % 16, ty = tid / 16;
    int row0 = bm * BM, col0 = bn * BN;
    float acc[4][4] = {};
    for (int k0 = 0; k0 < K; k0 += BKK) {
        for (int i = tid; i < BM * BKK; i += 256) {
            int r = i / BKK, c = i % BKK;
            int gr = row0 + r;
            As2[c][r] = (gr < M) ? A[(size_t)gr * K + (k0 + c)] : 0.f;
        }
        for (int i = tid; i < BN * BKK; i += 256) {
            int r = i / BKK, c = i % BKK;
            int gr = col0 + r;
            Bs2[c][r] = (gr < N) ? B[(size_t)gr * K + (k0 + c)] : 0.f;
        }
        __syncthreads();
        #pragma unroll
        for (int kk = 0; kk < BKK; ++kk) {
            f32x4 av = *(const f32x4*)&As2[kk][ty * 4];
            f32x4 bv = *(const f32x4*)&Bs2[kk][tx * 4];
            #pragma unroll
            for (int i = 0; i < 4; ++i)
                #pragma unroll
                for (int j = 0; j < 4; ++j) acc[i][j] += av[i] * bv[j];
        }
        __syncthreads();
    }
    for (int i = 0; i < 4; ++i) {
        int r = row0 + ty * 4 + i;
        if (r >= M) continue;
        for (int j = 0; j < 4; ++j) {
            int c = col0 + tx * 4 + j;
            if (c < N) C[(size_t)r * N + c] = acc[i][j];
        }
    }
}

// ---------------- RMSNorm rows (in-place safe) ----------------
__global__ __launch_bounds__(256) void rmsnorm_rows(const float* __restrict__ x,
                                                    const float* __restrict__ w,
                                                    float* __restrict__ y, int ncols) {
    int row = blockIdx.x, tid = threadIdx.x;
    const float* xr = x + (size_t)row * ncols;
    float ss = 0.f;
    for (int c = tid; c < ncols; c += 256) { float v = xr[c]; ss += v * v; }
    __shared__ float red[4];
    ss = wave_reduce_sum(ss);
    if ((tid & 63) == 0) red[tid >> 6] = ss;
    __syncthreads();
    float tot = red[0] + red[1] + red[2] + red[3];
    float inv = rsqrtf(tot / (float)ncols + EPSF);
    for (int c = tid; c < ncols; c += 256)
        y[(size_t)row * ncols + c] = xr[c] * inv * w[c];
}

// ---------------- rope q (bf16 in), write into Qeff[...,512:576] ----------------
__global__ __launch_bounds__(256) void rope_qeff(const __bf16* __restrict__ qbuf,
                                                 const float* __restrict__ cosT,
                                                 const float* __restrict__ sinT,
                                                 __bf16* __restrict__ qeff) {
    int s = blockIdx.x;
    for (int i = threadIdx.x; i < NHEAD * 32; i += 256) {
        int h = i >> 5, d = i & 31;
        const __bf16* base = qbuf + (size_t)s * (NHEAD * QKHEAD) + h * QKHEAD + QKNOPE;
        float x1 = (float)base[d], x2 = (float)base[d + 32];
        float c1 = cosT[s * 64 + d],      s1 = sinT[s * 64 + d];
        float c2 = cosT[s * 64 + d + 32], s2 = sinT[s * 64 + d + 32];
        __bf16* o = qeff + (size_t)s * (NHEAD * DLAT) + h * DLAT + 512;
        o[d]      = (__bf16)(x1 * c1 - x2 * s1);
        o[d + 32] = (__bf16)(x2 * c2 + x1 * s2);
    }
}

// ---------------- kv post: rmsnorm 512 + rope 64 -> Klat[2048,576] bf16 ----------------
__global__ __launch_bounds__(256) void kv_post(const float* __restrict__ kv,
                                               const float* __restrict__ kvw,
                                               const float* __restrict__ cosT,
                                               const float* __restrict__ sinT,
                                               __bf16* __restrict__ klat) {
    int s = blockIdx.x, tid = threadIdx.x;
    const float* row = kv + (size_t)s * DLAT;
    float ss = 0.f;
    for (int c = tid; c < KVLORA; c += 256) { float v = row[c]; ss += v * v; }
    __shared__ float red[4];
    ss = wave_reduce_sum(ss);
    if ((tid & 63) == 0) red[tid >> 6] = ss;
    __syncthreads();
    float tot = red[0] + red[1] + red[2] + red[3];
    float inv = rsqrtf(tot / (float)KVLORA + EPSF);
    __bf16* orow = klat + (size_t)s * DLAT;
    for (int c = tid; c < KVLORA; c += 256)
        orow[c] = (__bf16)(row[c] * inv * kvw[c]);
    if (tid < 32) {
        int d = tid;
        float x1 = row[KVLORA + d], x2 = row[KVLORA + d + 32];
        float c1 = cosT[s * 64 + d],      s1 = sinT[s * 64 + d];
        float c2 = cosT[s * 64 + d + 32], s2 = sinT[s * 64 + d + 32];
        orow[512 + d]      = (__bf16)(x1 * c1 - x2 * s1);
        orow[512 + d + 32] = (__bf16)(x2 * c2 + x1 * s2);
    }
}

// ---------------- ik post: layer_norm(128) + rope first 64 (f32) ----------------
__global__ __launch_bounds__(128) void ik_post(const float* __restrict__ ikraw,
                                               const float* __restrict__ w,
                                               const float* __restrict__ b,
                                               const float* __restrict__ cosT,
                                               const float* __restrict__ sinT,
                                               float* __restrict__ ikbuf) {
    int s = blockIdx.x, tid = threadIdx.x;
    float x = ikraw[(size_t)s * DIN + tid];
    __shared__ float redA[2], redB[2], sy[DIN];
    float sm = wave_reduce_sum(x);
    if ((tid & 63) == 0) redA[tid >> 6] = sm;
    __syncthreads();
    float mean = (redA[0] + redA[1]) / (float)DIN;
    float dx = x - mean;
    float vs = wave_reduce_sum(dx * dx);
    if ((tid & 63) == 0) redB[tid >> 6] = vs;
    __syncthreads();
    float var = (redB[0] + redB[1]) / (float)DIN;
    sy[tid] = dx * rsqrtf(var + EPSF) * w[tid] + b[tid];
    __syncthreads();
    float* outr = ikbuf + (size_t)s * DIN;
    if (tid < 32) {
        int d = tid;
        float c1 = cosT[s * 64 + d],      s1 = sinT[s * 64 + d];
        float c2 = cosT[s * 64 + d + 32], s2 = sinT[s * 64 + d + 32];
        outr[d]      = sy[d] * c1 - sy[d + 32] * s1;
        outr[d + 32] = sy[d + 32] * c2 + sy[d] * s2;
    } else if (tid >= 64) {
        outr[tid] = sy[tid];
    }
}

// ---------------- cq: fold iw into roped iq; scale 1/32 (f32) ----------------
__global__ __launch_bounds__(128) void cq_kernel(const float* __restrict__ iqraw,
                                                 const float* __restrict__ iwbuf,
                                                 const float* __restrict__ cosT,
                                                 const float* __restrict__ sinT,
                                                 float* __restrict__ cqbuf) {
    int s = blockIdx.x, d = threadIdx.x;
    __shared__ float siw[HIN];
    if (d < HIN) siw[d] = iwbuf[(size_t)s * HIN + d];
    __syncthreads();
    float acc = 0.f;
    float c1 = 0.f, s1 = 0.f;
    if (d < 64) { c1 = cosT[s * 64 + d]; s1 = sinT[s * 64 + d]; }
    #pragma unroll
    for (int h = 0; h < HIN; ++h) {
        const float* base = iqraw + ((size_t)s * HIN + h) * DIN;
        float v;
        if (d < 32)       v = base[d] * c1 - base[d + 32] * s1;
        else if (d < 64)  v = base[d] * c1 + base[d - 32] * s1;
        else              v = base[d];
        acc += siw[h] * v;
    }
    cqbuf[(size_t)s * DIN + d] = acc * 0.03125f;
}

// ---------------- exact top-512 per row (rows q >= 512), radix select ----------------
__global__ __launch_bounds__(256) void topk_rows(const float* __restrict__ iscore,
                                                 int* __restrict__ topk) {
    int q = TOPKN + blockIdx.x;
    int n = q + 1;
    __shared__ uint32_t skey[S_LEN];
    __shared__ int hist[256];
    __shared__ uint32_t sp;
    __shared__ int sr, pos;
    int tid = threadIdx.x;
    const float* row = iscore + (size_t)q * S_LEN;
    for (int i = tid; i < n; i += 256) {
        uint32_t u = __float_as_uint(row[i]);
        skey[i] = (u & 0x80000000u) ? ~u : (u | 0x80000000u);
    }
    __syncthreads();
    uint32_t prefix = 0;
    int remk = TOPKN;
    for (int pass = 0; pass < 4; ++pass) {
        int shift = 24 - 8 * pass;
        uint32_t pmask = pass ? (0xFFFFFFFFu << (shift + 8)) : 0u;
        for (int i = tid; i < 256; i += 256) hist[i] = 0;
        __syncthreads();
        for (int i = tid; i < n; i += 256) {
            uint32_t u = skey[i];
            if ((u & pmask) == prefix) atomicAdd(&hist[(u >> shift) & 255], 1);
        }
        __syncthreads();
        if (tid == 0) {
            int cum = 0;
            for (int bkt = 255; bkt >= 0; --bkt) {
                int nc = cum + hist[bkt];
                if (nc >= remk) { sp = prefix | ((uint32_t)bkt << shift); sr = remk - cum; break; }
                cum = nc;
            }
        }
        __syncthreads();
        prefix = sp; remk = sr;
        __syncthreads();
    }
    if (tid == 0) pos = 0;
    __syncthreads();
    int* orow = topk + (size_t)q * TOPKN;
    for (int i = tid; i < n; i += 256) {
        if (skey[i] > prefix) { int p = atomicAdd(&pos, 1); orow[p] = i; }
    }
    __syncthreads();
    if (tid == 0) {
        int p = pos;
        for (int i = 0; i < n && remk > 0; ++i) {
            if (skey[i] == prefix) { orow[p++] = i; --remk; }
        }
    }
}

// ---------------- absorbed-MLA flash attention: one workgroup per q --------------
// S[16h,32k] via MFMA (k-split across wave pairs), online softmax,
// O_lat[16h,512c] += P[16,32]*Vlat[32,512] via MFMA (dims split across 4 waves).
#define SKS 584   // shorts per sK row (1168 B; 292 dwords, %32==4 -> 2-way on b128)
__global__ __launch_bounds__(256) void attn2(const __bf16* __restrict__ qeff,
                                             const __bf16* __restrict__ klat,
                                             const int* __restrict__ topk,
                                             __bf16* __restrict__ o_lat) {
    int q = blockIdx.x;
    int tid = threadIdx.x;
    int lane = tid & 63, wid = tid >> 6;
    int l16 = lane & 15, quad = lane >> 4;
    int wn = wid & 1, wk = wid >> 1;

    __shared__ short sK[32 * SKS];         // 37376 B : 32 Klat rows (576 bf16 + pad)
    __shared__ float s_part[2][16][36];    // partial S from the two k-halves
    __shared__ float s_S[16][36];          // P (probabilities)
    __shared__ float s_m[16], s_l[16], s_alpha[16], s_inv[16];

    int L = (q < TOPKN) ? (q + 1) : TOPKN;
    int nt = (L + 31) >> 5;
    const int* idxr = topk + (size_t)q * TOPKN;

    // preload Qeff A-frags (m=head=l16, k-dims of this wave's half)
    bf16x8 qf[9];
    const __bf16* qrow = qeff + (size_t)q * (NHEAD * DLAT) + l16 * DLAT + wk * 288 + quad * 8;
    #pragma unroll
    for (int s = 0; s < 9; ++s) qf[s] = *(const bf16x8*)(qrow + s * 32);

    if (tid < 16) { s_m[tid] = -1e30f; s_l[tid] = 0.f; }

    f32x4 oacc[8];
    #pragma unroll
    for (int i = 0; i < 8; ++i) oacc[i] = (f32x4){0.f, 0.f, 0.f, 0.f};

    int srow = tid >> 3, schk = tid & 7;   // staging: 8 threads/row, 144 B each

    for (int t = 0; t < nt; ++t) {
        // ---- stage 32 gathered Klat rows into LDS ----
        int ki = t * 32 + srow;
        int gk = 0;
        if (ki < L) gk = (q < TOPKN) ? ki : idxr[ki];
        const uint4* src = (const uint4*)(klat + (size_t)gk * DLAT) + schk * 9;
        uint4* dst = (uint4*)((char*)sK + srow * (SKS * 2) + schk * 144);
        #pragma unroll
        for (int c = 0; c < 9; ++c) dst[c] = src[c];
        __syncthreads();

        // ---- S partial: wave (wn,wk): 16 keys x 288 dims ----
        f32x4 sacc = {0.f, 0.f, 0.f, 0.f};
        const short* kbase = sK + (wn * 16 + l16) * SKS + wk * 288 + quad * 8;
        #pragma unroll
        for (int s = 0; s < 9; ++s) {
            bf16x8 kf = *(const bf16x8*)(kbase + s * 32);
            sacc = __builtin_amdgcn_mfma_f32_16x16x32_bf16(qf[s], kf, sacc, 0, 0, 0);
        }
        #pragma unroll
        for (int r = 0; r < 4; ++r)
            s_part[wk][quad * 4 + r][wn * 16 + l16] = sacc[r];
        __syncthreads();

        // ---- parallel online softmax: thread group (16/head) handles 2 keys ----
        {
            int h = tid >> 4, k0 = (tid & 15) * 2;
            float v0 = -1e30f, v1 = -1e30f;
            if (t * 32 + k0 < L)
                v0 = (s_part[0][h][k0] + s_part[1][h][k0]) * SCALE_ATT;
            if (t * 32 + k0 + 1 < L)
                v1 = (s_part[0][h][k0 + 1] + s_part[1][h][k0 + 1]) * SCALE_ATT;
            float mt = fmaxf(v0, v1);
            #pragma unroll
            for (int o = 1; o < 16; o <<= 1) mt = fmaxf(mt, __shfl_xor(mt, o));
            float mold = s_m[h];                 // read before lane0 writes (wave-lockstep)
            float mnew = fmaxf(mold, mt);
            float p0 = __expf(v0 - mnew), p1 = __expf(v1 - mnew);
            float ls = p0 + p1;
            #pragma unroll
            for (int o = 1; o < 16; o <<= 1) ls += __shfl_xor(ls, o);
            s_S[h][k0] = p0; s_S[h][k0 + 1] = p1;
            if ((tid & 15) == 0) {
                float alpha = __expf(mold - mnew);
                s_alpha[h] = alpha;
                s_m[h] = mnew;
                s_l[h] = s_l[h] * alpha + ls;
            }
        }
        __syncthreads();

        // ---- PV: each wave covers 128 latent dims; K=32 keys in one MFMA ----
        f32x4 al4 = *(const f32x4*)&s_alpha[quad * 4];
        f32x4 p0v = *(const f32x4*)&s_S[l16][quad * 8];
        f32x4 p1v = *(const f32x4*)&s_S[l16][quad * 8 + 4];
        bf16x8 pf;
        pf[0] = (__bf16)p0v[0]; pf[1] = (__bf16)p0v[1];
        pf[2] = (__bf16)p0v[2]; pf[3] = (__bf16)p0v[3];
        pf[4] = (__bf16)p1v[0]; pf[5] = (__bf16)p1v[1];
        pf[6] = (__bf16)p1v[2]; pf[7] = (__bf16)p1v[3];
        const __bf16* sKb = (const __bf16*)sK;
        #pragma unroll
        for (int n = 0; n < 8; ++n) {
            int dim = wid * 128 + n * 16 + l16;
            bf16x8 vf;
            #pragma unroll
            for (int j = 0; j < 8; ++j)
                vf[j] = sKb[(quad * 8 + j) * SKS + dim];
            #pragma unroll
            for (int r = 0; r < 4; ++r) oacc[n][r] *= al4[r];
            oacc[n] = __builtin_amdgcn_mfma_f32_16x16x32_bf16(pf, vf, oacc[n], 0, 0, 0);
        }
        __syncthreads();
    }

    if (tid < 16) s_inv[tid] = 1.f / s_l[tid];
    __syncthreads();
    f32x4 inv4 = *(const f32x4*)&s_inv[quad * 4];
    #pragma unroll
    for (int n = 0; n < 8; ++n) {
        int dim = wid * 128 + n * 16 + l16;
        #pragma unroll
        for (int r = 0; r < 4; ++r) {
            int h = quad * 4 + r;
            o_lat[(size_t)q * 8192 + h * 512 + dim] = (__bf16)(oacc[n][r] * inv4[r]);
        }
    }
}

extern "C" void kernel_launch(void* const* d_in, const int* in_sizes, int n_in,
                              void* d_out, int out_size, void* d_ws, size_t ws_size,
                              hipStream_t stream) {
    const float* hid          = (const float*)d_in[0];
    const float* cosT         = (const float*)d_in[1];
    const float* sinT         = (const float*)d_in[2];
    const float* wq_a         = (const float*)d_in[3];
    const float* q_a_norm_w   = (const float*)d_in[4];
    const float* wq_b         = (const float*)d_in[5];
    const float* wkv_a        = (const float*)d_in[6];
    const float* kv_a_norm_w  = (const float*)d_in[7];
    const float* wkv_b        = (const float*)d_in[8];
    const float* wo           = (const float*)d_in[9];
    const float* idx_wq_b     = (const float*)d_in[10];
    const float* idx_wk       = (const float*)d_in[11];
    const float* idx_k_norm_w = (const float*)d_in[12];
    const float* idx_k_norm_b = (const float*)d_in[13];
    const float* idx_weights_w= (const float*)d_in[14];
    float* out = (float*)d_out;

    char* ws = (char*)d_ws;
    size_t off = 0;
    auto alloc = [&](size_t nbytes) {
        void* p = (void*)(ws + off);
        off += (nbytes + 255) & ~(size_t)255;
        return p;
    };
    float*  q_lora   = (float*) alloc((size_t)S_LEN * QLORA * 4);
    __bf16* qbuf_bf  = (__bf16*)alloc((size_t)S_LEN * NHEAD * QKHEAD * 2);
    float*  kv       = (float*) alloc((size_t)S_LEN * DLAT * 4);
    __bf16* klat_bf  = (__bf16*)alloc((size_t)S_LEN * DLAT * 2);
    __bf16* qeff_bf  = (__bf16*)alloc((size_t)S_LEN * NHEAD * DLAT * 2);
    // union A: q_lora_bf (early, 3.1MB) / topk (late, 4.2MB)
    char* uA = (char*)alloc((size_t)S_LEN * TOPKN * 4);
    __bf16* q_lora_bf = (__bf16*)uA;
    int*    topk      = (int*)uA;
    // union B: [hid_bf | wkv_a_bf] (early, 10.7MB) / attn_o_bf (late, 8.4MB)
    char* uB = (char*)alloc((size_t)S_LEN * HIDDEN * 2 + (size_t)DLAT * HIDDEN * 2);
    __bf16* hid_bf    = (__bf16*)uB;
    __bf16* wkv_a_bf  = (__bf16*)(uB + (size_t)S_LEN * HIDDEN * 2);
    __bf16* attn_o_bf = (__bf16*)uB;
    // union C: indexer block (early, 28.4MB) / o_lat (late, 33.6MB)
    char* uC = (char*)alloc((size_t)S_LEN * NHEAD * 512 * 2);
    __bf16* o_lat_bf = (__bf16*)uC;
    float* iqraw  = (float*)uC;
    float* ikraw  = (float*)(uC + 8388608);
    float* ikbuf  = (float*)(uC + 9437184);
    float* iwbuf  = (float*)(uC + 10485760);
    float* cqbuf  = (float*)(uC + 10551296);
    float* iscore = (float*)(uC + 11599872);   // 16.8MB, ends at 28.4MB < 33.6MB
    __bf16* wq_b_bf  = (__bf16*)alloc((size_t)(NHEAD * QKHEAD) * QLORA * 2);
    __bf16* wkv_b_bf = (__bf16*)alloc((size_t)(NHEAD * 256) * KVLORA * 2);
    __bf16* wknt_bf  = (__bf16*)alloc((size_t)NHEAD * 512 * 128 * 2);
    __bf16* wo_bf    = (__bf16*)alloc((size_t)HIDDEN * (NHEAD * VDIM) * 2);
    (void)ws_size; (void)in_sizes; (void)n_in; (void)out_size;

    dim3 blk(256);
    auto grd = [](int M, int N) { return dim3((N + BN - 1) / BN, (M + BM - 1) / BM); };
    auto cst = [&](const float* src, __bf16* dst, int n) {
        cast4<<<(n / 4 + 255) / 256, blk, 0, stream>>>(src, dst, n);
    };

    // casts + weight transpose
    cst(hid,   hid_bf,   S_LEN * HIDDEN);
    cst(wq_b,  wq_b_bf,  NHEAD * QKHEAD * QLORA);
    cst(wkv_a, wkv_a_bf, DLAT * HIDDEN);
    cst(wkv_b, wkv_b_bf, NHEAD * 256 * KVLORA);
    cst(wo,    wo_bf,    HIDDEN * NHEAD * VDIM);
    transpose_wkn<<<NHEAD * 512 * 128 / 256, blk, 0, stream>>>(wkv_b, wknt_bf);

    // q path (q_lora stays f32 for the indexer)
    gemm_xt<<<grd(S_LEN, QLORA), blk, 0, stream>>>(hid, wq_a, q_lora, S_LEN, QLORA, HIDDEN);
    rmsnorm_rows<<<S_LEN, 256, 0, stream>>>(q_lora, q_a_norm_w, q_lora, QLORA);
    cst(q_lora, q_lora_bf, S_LEN * QLORA);
    gemm_s<__bf16><<<dim3((NHEAD * QKHEAD) / GBN, S_LEN / GBM, 1), blk, 0, stream>>>(
        q_lora_bf, wq_b_bf, qbuf_bf, S_LEN, NHEAD * QKHEAD, QLORA,
        QLORA, QLORA, NHEAD * QKHEAD, 0, 0, 0);
    rope_qeff<<<S_LEN, 256, 0, stream>>>(qbuf_bf, cosT, sinT, qeff_bf);
    // Qeff nope: batched per head: C[q,c] = sum_d q_nope[q,h,d]*wkv_b[h*256+d,c]
    gemm_s<__bf16><<<dim3(512 / GBN, S_LEN / GBM, NHEAD), blk, 0, stream>>>(
        qbuf_bf, wknt_bf, qeff_bf, S_LEN, 512, 128,
        NHEAD * QKHEAD, 128, NHEAD * DLAT, QKHEAD, 512 * 128, DLAT);
    // kv path -> Klat
    gemm_s<float><<<dim3(DLAT / GBN, S_LEN / GBM, 1), blk, 0, stream>>>(
        hid_bf, wkv_a_bf, kv, S_LEN, DLAT, HIDDEN, HIDDEN, HIDDEN, DLAT, 0, 0, 0);
    kv_post<<<S_LEN, 256, 0, stream>>>(kv, kv_a_norm_w, cosT, sinT, klat_bf);
    // indexer (all f32 — top-k set membership is precision-sensitive)
    gemm_xt<<<grd(S_LEN, HIN * DIN), blk, 0, stream>>>(q_lora, idx_wq_b, iqraw, S_LEN, HIN * DIN, QLORA);
    gemm_xt<<<grd(S_LEN, DIN), blk, 0, stream>>>(hid, idx_wk, ikraw, S_LEN, DIN, HIDDEN);
    ik_post<<<S_LEN, 128, 0, stream>>>(ikraw, idx_k_norm_w, idx_k_norm_b, cosT, sinT, ikbuf);
    gemm_xt<<<grd(S_LEN, HIN), blk, 0, stream>>>(hid, idx_weights_w, iwbuf, S_LEN, HIN, HIDDEN);
    cq_kernel<<<S_LEN, 128, 0, stream>>>(iqraw, iwbuf, cosT, sinT, cqbuf);
    gemm_xt<<<grd(S_LEN, S_LEN), blk, 0, stream>>>(cqbuf, ikbuf, iscore, S_LEN, S_LEN, DIN);
    topk_rows<<<S_LEN - TOPKN, 256, 0, stream>>>(iscore, topk);
    // absorbed attention -> o_lat
    attn2<<<S_LEN, 256, 0, stream>>>(qeff_bf, klat_bf, topk, o_lat_bf);
    // V projection per head: attn_o[q, h*128+n] = sum_c o_lat[q,h,c]*wkv_b[h*256+128+n, c]
    gemm_s<__bf16><<<dim3(VDIM / GBN, S_LEN / GBM, NHEAD), blk, 0, stream>>>(
        o_lat_bf, wkv_b_bf + 128 * 512, attn_o_bf, S_LEN, VDIM, 512,
        NHEAD * 512, 512, NHEAD * VDIM, 512, 256 * 512, VDIM);
    // output projection
    gemm_s<float><<<dim3(HIDDEN / GBN, S_LEN / GBM, 1), blk, 0, stream>>>(
        attn_o_bf, wo_bf, out, S_LEN, HIDDEN, NHEAD * VDIM,
        NHEAD * VDIM, NHEAD * VDIM, HIDDEN, 0, 0, 0);
}

// Round 4
// 853.716 us; speedup vs baseline: 5.6677x; 1.9899x over previous
//
#include <hip/hip_runtime.h>
#include <hip/hip_bf16.h>
#include <stdint.h>
#include <math.h>

#define S_LEN 2048
#define HIDDEN 2048
#define NHEAD 16
#define QLORA 768
#define KVLORA 512
#define QKNOPE 128
#define QKROPE 64
#define QKHEAD 192
#define VDIM 128
#define HIN 8
#define DIN 128
#define TOPKN 512
#define EPSF 1e-5f
#define DLAT 576           // 512 latent + 64 rope
#define SCALE_ATT 0.07216878364870322f  // 192^-0.5

typedef __bf16 bf16x8 __attribute__((ext_vector_type(8)));
typedef float  f32x4  __attribute__((ext_vector_type(4)));

static __device__ __forceinline__ float wave_reduce_sum(float v) {
    #pragma unroll
    for (int off = 32; off > 0; off >>= 1) v += __shfl_down(v, off);
    return v;
}

// ---------------- cast f32 -> bf16, 4 elems/thread ----------------
__global__ __launch_bounds__(256) void cast4(const float* __restrict__ in,
                                             __bf16* __restrict__ out, int n) {
    int i = (blockIdx.x * 256 + threadIdx.x) * 4;
    if (i < n) {
        f32x4 v = *(const f32x4*)(in + i);
        out[i + 0] = (__bf16)v[0];
        out[i + 1] = (__bf16)v[1];
        out[i + 2] = (__bf16)v[2];
        out[i + 3] = (__bf16)v[3];
    }
}

// ---------------- split f32 -> hi bf16 + lo bf16 (bf16x3 trick) ----------------
__global__ __launch_bounds__(256) void split4(const float* __restrict__ in,
                                              __bf16* __restrict__ hi,
                                              __bf16* __restrict__ lo, int n) {
    int i = (blockIdx.x * 256 + threadIdx.x) * 4;
    if (i < n) {
        f32x4 v = *(const f32x4*)(in + i);
        #pragma unroll
        for (int j = 0; j < 4; ++j) {
            __bf16 h = (__bf16)v[j];
            hi[i + j] = h;
            lo[i + j] = (__bf16)(v[j] - (float)h);
        }
    }
}

// wknt[h][c][d] = wkv_b[(h*256+d)*512 + c]  (per-head K-nope weight, transposed, bf16)
__global__ __launch_bounds__(256) void transpose_wkn(const float* __restrict__ wkv_b,
                                                     __bf16* __restrict__ wknt) {
    int t = blockIdx.x * 256 + threadIdx.x;       // 16*512*128 total
    int c = t & 511, d = (t >> 9) & 127, h = t >> 16;
    wknt[(size_t)h * 65536 + c * 128 + d] =
        (__bf16)wkv_b[((size_t)(h * 256 + d)) * 512 + c];
}

// ---------------- bf16 MFMA GEMM (strided, batched): C = A*B^T ----------------
// Block tile 128x64, BK=32, 4 waves. M%128==0, N%64==0, K%32==0.
#define GBM 128
#define GBN 64
#define GBK 32
template <typename OutT>
__global__ __launch_bounds__(256) void gemm_s(const __bf16* __restrict__ A,
                                              const __bf16* __restrict__ B,
                                              OutT* __restrict__ C,
                                              int M, int N, int K,
                                              int lda, int ldb, int ldc,
                                              long sA, long sB, long sC) {
    A += (size_t)blockIdx.z * sA;
    B += (size_t)blockIdx.z * sB;
    C += (size_t)blockIdx.z * sC;
    __shared__ __bf16 sAs[GBM * GBK];
    __shared__ __bf16 sBs[GBN * GBK];
    int tid = threadIdx.x;
    int lane = tid & 63, wid = tid >> 6;
    int quad = lane >> 4, l16 = lane & 15;
    int wm = wid >> 1, wn = wid & 1;
    int row0 = blockIdx.y * GBM, col0 = blockIdx.x * GBN;

    f32x4 acc[4][2] = {};
    int am = tid >> 1, ah = tid & 1;
    int bn = tid >> 2, bq = tid & 3;

    for (int k0 = 0; k0 < K; k0 += GBK) {
        const uint4* ga = (const uint4*)(A + (size_t)(row0 + am) * lda + k0 + ah * 16);
        uint4* da = (uint4*)&sAs[am * GBK + ah * 16];
        da[0] = ga[0];
        da[1] = ga[1];
        *(uint4*)&sBs[bn * GBK + bq * 8] =
            *(const uint4*)(B + (size_t)(col0 + bn) * ldb + k0 + bq * 8);
        __syncthreads();
        bf16x8 af[4], bfr[2];
        #pragma unroll
        for (int mi = 0; mi < 4; ++mi)
            af[mi] = *(const bf16x8*)&sAs[(wm * 64 + mi * 16 + l16) * GBK + quad * 8];
        #pragma unroll
        for (int ni = 0; ni < 2; ++ni)
            bfr[ni] = *(const bf16x8*)&sBs[(wn * 32 + ni * 16 + l16) * GBK + quad * 8];
        #pragma unroll
        for (int mi = 0; mi < 4; ++mi)
            #pragma unroll
            for (int ni = 0; ni < 2; ++ni)
                acc[mi][ni] = __builtin_amdgcn_mfma_f32_16x16x32_bf16(
                    af[mi], bfr[ni], acc[mi][ni], 0, 0, 0);
        __syncthreads();
    }
    #pragma unroll
    for (int mi = 0; mi < 4; ++mi)
        #pragma unroll
        for (int ni = 0; ni < 2; ++ni)
            #pragma unroll
            for (int r = 0; r < 4; ++r) {
                int row = row0 + wm * 64 + mi * 16 + quad * 4 + r;
                int col = col0 + wn * 32 + ni * 16 + l16;
                C[(size_t)row * ldc + col] = (OutT)acc[mi][ni][r];
            }
}

// ------------- split-bf16 (~f32 accuracy) MFMA GEMM: C = A*B^T -------------
// A given as (Ah,Al), B as (Bh,Bl); C = Ah*Bh + Ah*Bl + Al*Bh. f32 out.
// Optional causal block-skip (keys = cols): skip blocks fully above diagonal.
template <bool CAUSAL>
__global__ __launch_bounds__(256) void gemm3(const __bf16* __restrict__ Ah,
                                             const __bf16* __restrict__ Al,
                                             const __bf16* __restrict__ Bh,
                                             const __bf16* __restrict__ Bl,
                                             float* __restrict__ C,
                                             int M, int N, int K,
                                             int lda, int ldb, int ldc,
                                             int row_base) {
    int row0 = blockIdx.y * GBM + row_base, col0 = blockIdx.x * GBN;
    if (CAUSAL && col0 > row0 + GBM - 1) return;
    __shared__ __bf16 sAh[GBM * GBK], sAl[GBM * GBK];
    __shared__ __bf16 sBh[GBN * GBK], sBl[GBN * GBK];
    int tid = threadIdx.x;
    int lane = tid & 63, wid = tid >> 6;
    int quad = lane >> 4, l16 = lane & 15;
    int wm = wid >> 1, wn = wid & 1;

    f32x4 acc[4][2] = {};
    int am = tid >> 1, ah = tid & 1;
    int bn = tid >> 2, bq = tid & 3;

    for (int k0 = 0; k0 < K; k0 += GBK) {
        size_t aoff = (size_t)(row0 + am) * lda + k0 + ah * 16;
        uint4* dah = (uint4*)&sAh[am * GBK + ah * 16];
        uint4* dal = (uint4*)&sAl[am * GBK + ah * 16];
        dah[0] = ((const uint4*)(Ah + aoff))[0];
        dah[1] = ((const uint4*)(Ah + aoff))[1];
        dal[0] = ((const uint4*)(Al + aoff))[0];
        dal[1] = ((const uint4*)(Al + aoff))[1];
        size_t boff = (size_t)(col0 + bn) * ldb + k0 + bq * 8;
        *(uint4*)&sBh[bn * GBK + bq * 8] = *(const uint4*)(Bh + boff);
        *(uint4*)&sBl[bn * GBK + bq * 8] = *(const uint4*)(Bl + boff);
        __syncthreads();
        bf16x8 afh[4], afl[4], bfh[2], bfl[2];
        #pragma unroll
        for (int mi = 0; mi < 4; ++mi) {
            int o = (wm * 64 + mi * 16 + l16) * GBK + quad * 8;
            afh[mi] = *(const bf16x8*)&sAh[o];
            afl[mi] = *(const bf16x8*)&sAl[o];
        }
        #pragma unroll
        for (int ni = 0; ni < 2; ++ni) {
            int o = (wn * 32 + ni * 16 + l16) * GBK + quad * 8;
            bfh[ni] = *(const bf16x8*)&sBh[o];
            bfl[ni] = *(const bf16x8*)&sBl[o];
        }
        #pragma unroll
        for (int mi = 0; mi < 4; ++mi)
            #pragma unroll
            for (int ni = 0; ni < 2; ++ni) {
                acc[mi][ni] = __builtin_amdgcn_mfma_f32_16x16x32_bf16(
                    afl[mi], bfh[ni], acc[mi][ni], 0, 0, 0);
                acc[mi][ni] = __builtin_amdgcn_mfma_f32_16x16x32_bf16(
                    afh[mi], bfl[ni], acc[mi][ni], 0, 0, 0);
                acc[mi][ni] = __builtin_amdgcn_mfma_f32_16x16x32_bf16(
                    afh[mi], bfh[ni], acc[mi][ni], 0, 0, 0);
            }
        __syncthreads();
    }
    #pragma unroll
    for (int mi = 0; mi < 4; ++mi)
        #pragma unroll
        for (int ni = 0; ni < 2; ++ni)
            #pragma unroll
            for (int r = 0; r < 4; ++r) {
                int row = row0 + wm * 64 + mi * 16 + quad * 4 + r;
                int col = col0 + wn * 32 + ni * 16 + l16;
                C[(size_t)row * ldc + col] = acc[mi][ni][r];
            }
}

// ---------------- iw dots: iw[q,h] = hid[q,:]·idx_weights_w[h,:] ----------------
__global__ __launch_bounds__(256) void iw_dots(const float* __restrict__ hid,
                                               const float* __restrict__ w,
                                               float* __restrict__ iw) {
    int q = blockIdx.x, tid = threadIdx.x;
    int lane = tid & 63, wid = tid >> 6;
    float acc[HIN] = {};
    const float* xr = hid + (size_t)q * HIDDEN;
    for (int c = tid; c < HIDDEN; c += 256) {
        float x = xr[c];
        #pragma unroll
        for (int h = 0; h < HIN; ++h) acc[h] += x * w[h * HIDDEN + c];
    }
    __shared__ float red[4][HIN];
    #pragma unroll
    for (int h = 0; h < HIN; ++h) acc[h] = wave_reduce_sum(acc[h]);
    if (lane == 0)
        #pragma unroll
        for (int h = 0; h < HIN; ++h) red[wid][h] = acc[h];
    __syncthreads();
    if (tid < HIN)
        iw[(size_t)q * HIN + tid] = red[0][tid] + red[1][tid] + red[2][tid] + red[3][tid];
}

// ---------------- RMSNorm rows (in-place safe) ----------------
__global__ __launch_bounds__(256) void rmsnorm_rows(const float* __restrict__ x,
                                                    const float* __restrict__ w,
                                                    float* __restrict__ y, int ncols) {
    int row = blockIdx.x, tid = threadIdx.x;
    const float* xr = x + (size_t)row * ncols;
    float ss = 0.f;
    for (int c = tid; c < ncols; c += 256) { float v = xr[c]; ss += v * v; }
    __shared__ float red[4];
    ss = wave_reduce_sum(ss);
    if ((tid & 63) == 0) red[tid >> 6] = ss;
    __syncthreads();
    float tot = red[0] + red[1] + red[2] + red[3];
    float inv = rsqrtf(tot / (float)ncols + EPSF);
    for (int c = tid; c < ncols; c += 256)
        y[(size_t)row * ncols + c] = xr[c] * inv * w[c];
}

// ---------------- rope q (bf16 in), write into Qeff[...,512:576] ----------------
__global__ __launch_bounds__(256) void rope_qeff(const __bf16* __restrict__ qbuf,
                                                 const float* __restrict__ cosT,
                                                 const float* __restrict__ sinT,
                                                 __bf16* __restrict__ qeff) {
    int s = blockIdx.x;
    for (int i = threadIdx.x; i < NHEAD * 32; i += 256) {
        int h = i >> 5, d = i & 31;
        const __bf16* base = qbuf + (size_t)s * (NHEAD * QKHEAD) + h * QKHEAD + QKNOPE;
        float x1 = (float)base[d], x2 = (float)base[d + 32];
        float c1 = cosT[s * 64 + d],      s1 = sinT[s * 64 + d];
        float c2 = cosT[s * 64 + d + 32], s2 = sinT[s * 64 + d + 32];
        __bf16* o = qeff + (size_t)s * (NHEAD * DLAT) + h * DLAT + 512;
        o[d]      = (__bf16)(x1 * c1 - x2 * s1);
        o[d + 32] = (__bf16)(x2 * c2 + x1 * s2);
    }
}

// ---------------- kv post: rmsnorm 512 + rope 64 -> Klat[2048,576] bf16 ----------------
__global__ __launch_bounds__(256) void kv_post(const float* __restrict__ kv,
                                               const float* __restrict__ kvw,
                                               const float* __restrict__ cosT,
                                               const float* __restrict__ sinT,
                                               __bf16* __restrict__ klat) {
    int s = blockIdx.x, tid = threadIdx.x;
    const float* row = kv + (size_t)s * DLAT;
    float ss = 0.f;
    for (int c = tid; c < KVLORA; c += 256) { float v = row[c]; ss += v * v; }
    __shared__ float red[4];
    ss = wave_reduce_sum(ss);
    if ((tid & 63) == 0) red[tid >> 6] = ss;
    __syncthreads();
    float tot = red[0] + red[1] + red[2] + red[3];
    float inv = rsqrtf(tot / (float)KVLORA + EPSF);
    __bf16* orow = klat + (size_t)s * DLAT;
    for (int c = tid; c < KVLORA; c += 256)
        orow[c] = (__bf16)(row[c] * inv * kvw[c]);
    if (tid < 32) {
        int d = tid;
        float x1 = row[KVLORA + d], x2 = row[KVLORA + d + 32];
        float c1 = cosT[s * 64 + d],      s1 = sinT[s * 64 + d];
        float c2 = cosT[s * 64 + d + 32], s2 = sinT[s * 64 + d + 32];
        orow[512 + d]      = (__bf16)(x1 * c1 - x2 * s1);
        orow[512 + d + 32] = (__bf16)(x2 * c2 + x1 * s2);
    }
}

// ---------------- ik post: layer_norm(128) + rope first 64 (f32) ----------------
__global__ __launch_bounds__(128) void ik_post(const float* __restrict__ ikraw,
                                               const float* __restrict__ w,
                                               const float* __restrict__ b,
                                               const float* __restrict__ cosT,
                                               const float* __restrict__ sinT,
                                               float* __restrict__ ikbuf) {
    int s = blockIdx.x, tid = threadIdx.x;
    float x = ikraw[(size_t)s * DIN + tid];
    __shared__ float redA[2], redB[2], sy[DIN];
    float sm = wave_reduce_sum(x);
    if ((tid & 63) == 0) redA[tid >> 6] = sm;
    __syncthreads();
    float mean = (redA[0] + redA[1]) / (float)DIN;
    float dx = x - mean;
    float vs = wave_reduce_sum(dx * dx);
    if ((tid & 63) == 0) redB[tid >> 6] = vs;
    __syncthreads();
    float var = (redB[0] + redB[1]) / (float)DIN;
    sy[tid] = dx * rsqrtf(var + EPSF) * w[tid] + b[tid];
    __syncthreads();
    float* outr = ikbuf + (size_t)s * DIN;
    if (tid < 32) {
        int d = tid;
        float c1 = cosT[s * 64 + d],      s1 = sinT[s * 64 + d];
        float c2 = cosT[s * 64 + d + 32], s2 = sinT[s * 64 + d + 32];
        outr[d]      = sy[d] * c1 - sy[d + 32] * s1;
        outr[d + 32] = sy[d + 32] * c2 + sy[d] * s2;
    } else if (tid >= 64) {
        outr[tid] = sy[tid];
    }
}

// ---------------- cq: fold iw into roped iq; scale 1/32 (f32) ----------------
__global__ __launch_bounds__(128) void cq_kernel(const float* __restrict__ iqraw,
                                                 const float* __restrict__ iwbuf,
                                                 const float* __restrict__ cosT,
                                                 const float* __restrict__ sinT,
                                                 float* __restrict__ cqbuf) {
    int s = blockIdx.x, d = threadIdx.x;
    __shared__ float siw[HIN];
    if (d < HIN) siw[d] = iwbuf[(size_t)s * HIN + d];
    __syncthreads();
    float acc = 0.f;
    float c1 = 0.f, s1 = 0.f;
    if (d < 64) { c1 = cosT[s * 64 + d]; s1 = sinT[s * 64 + d]; }
    #pragma unroll
    for (int h = 0; h < HIN; ++h) {
        const float* base = iqraw + ((size_t)s * HIN + h) * DIN;
        float v;
        if (d < 32)       v = base[d] * c1 - base[d + 32] * s1;
        else if (d < 64)  v = base[d] * c1 + base[d - 32] * s1;
        else              v = base[d];
        acc += siw[h] * v;
    }
    cqbuf[(size_t)s * DIN + d] = acc * 0.03125f;
}

// ---------------- exact top-512 per row (rows q >= 512), radix select ----------------
__global__ __launch_bounds__(256) void topk_rows(const float* __restrict__ iscore,
                                                 int* __restrict__ topk) {
    int q = TOPKN + blockIdx.x;
    int n = q + 1;
    __shared__ uint32_t skey[S_LEN];
    __shared__ int hist[256];
    __shared__ uint32_t sp;
    __shared__ int sr, pos;
    int tid = threadIdx.x;
    const float* row = iscore + (size_t)q * S_LEN;
    for (int i = tid; i < n; i += 256) {
        uint32_t u = __float_as_uint(row[i]);
        skey[i] = (u & 0x80000000u) ? ~u : (u | 0x80000000u);
    }
    __syncthreads();
    uint32_t prefix = 0;
    int remk = TOPKN;
    for (int pass = 0; pass < 4; ++pass) {
        int shift = 24 - 8 * pass;
        uint32_t pmask = pass ? (0xFFFFFFFFu << (shift + 8)) : 0u;
        for (int i = tid; i < 256; i += 256) hist[i] = 0;
        __syncthreads();
        for (int i = tid; i < n; i += 256) {
            uint32_t u = skey[i];
            if ((u & pmask) == prefix) atomicAdd(&hist[(u >> shift) & 255], 1);
        }
        __syncthreads();
        if (tid == 0) {
            int cum = 0;
            for (int bkt = 255; bkt >= 0; --bkt) {
                int nc = cum + hist[bkt];
                if (nc >= remk) { sp = prefix | ((uint32_t)bkt << shift); sr = remk - cum; break; }
                cum = nc;
            }
        }
        __syncthreads();
        prefix = sp; remk = sr;
        __syncthreads();
    }
    if (tid == 0) pos = 0;
    __syncthreads();
    int* orow = topk + (size_t)q * TOPKN;
    for (int i = tid; i < n; i += 256) {
        if (skey[i] > prefix) { int p = atomicAdd(&pos, 1); orow[p] = i; }
    }
    __syncthreads();
    if (tid == 0) {
        int p = pos;
        for (int i = 0; i < n && remk > 0; ++i) {
            if (skey[i] == prefix) { orow[p++] = i; --remk; }
        }
    }
}

// ---------------- absorbed-MLA flash attention: one workgroup per q --------------
#define SKS 584   // shorts per sK row (1168 B)
__global__ __launch_bounds__(256) void attn2(const __bf16* __restrict__ qeff,
                                             const __bf16* __restrict__ klat,
                                             const int* __restrict__ topk,
                                             __bf16* __restrict__ o_lat) {
    int q = blockIdx.x;
    int tid = threadIdx.x;
    int lane = tid & 63, wid = tid >> 6;
    int l16 = lane & 15, quad = lane >> 4;
    int wn = wid & 1, wk = wid >> 1;

    __shared__ short sK[32 * SKS];
    __shared__ float s_part[2][16][36];
    __shared__ float s_S[16][36];
    __shared__ float s_m[16], s_l[16], s_alpha[16], s_inv[16];

    int L = (q < TOPKN) ? (q + 1) : TOPKN;
    int nt = (L + 31) >> 5;
    const int* idxr = topk + (size_t)q * TOPKN;

    bf16x8 qf[9];
    const __bf16* qrow = qeff + (size_t)q * (NHEAD * DLAT) + l16 * DLAT + wk * 288 + quad * 8;
    #pragma unroll
    for (int s = 0; s < 9; ++s) qf[s] = *(const bf16x8*)(qrow + s * 32);

    if (tid < 16) { s_m[tid] = -1e30f; s_l[tid] = 0.f; }

    f32x4 oacc[8];
    #pragma unroll
    for (int i = 0; i < 8; ++i) oacc[i] = (f32x4){0.f, 0.f, 0.f, 0.f};

    int srow = tid >> 3, schk = tid & 7;

    for (int t = 0; t < nt; ++t) {
        int ki = t * 32 + srow;
        int gk = 0;
        if (ki < L) gk = (q < TOPKN) ? ki : idxr[ki];
        const uint4* src = (const uint4*)(klat + (size_t)gk * DLAT) + schk * 9;
        uint4* dst = (uint4*)((char*)sK + srow * (SKS * 2) + schk * 144);
        #pragma unroll
        for (int c = 0; c < 9; ++c) dst[c] = src[c];
        __syncthreads();

        f32x4 sacc = {0.f, 0.f, 0.f, 0.f};
        const short* kbase = sK + (wn * 16 + l16) * SKS + wk * 288 + quad * 8;
        #pragma unroll
        for (int s = 0; s < 9; ++s) {
            bf16x8 kf = *(const bf16x8*)(kbase + s * 32);
            sacc = __builtin_amdgcn_mfma_f32_16x16x32_bf16(qf[s], kf, sacc, 0, 0, 0);
        }
        #pragma unroll
        for (int r = 0; r < 4; ++r)
            s_part[wk][quad * 4 + r][wn * 16 + l16] = sacc[r];
        __syncthreads();

        {
            int h = tid >> 4, k0 = (tid & 15) * 2;
            float v0 = -1e30f, v1 = -1e30f;
            if (t * 32 + k0 < L)
                v0 = (s_part[0][h][k0] + s_part[1][h][k0]) * SCALE_ATT;
            if (t * 32 + k0 + 1 < L)
                v1 = (s_part[0][h][k0 + 1] + s_part[1][h][k0 + 1]) * SCALE_ATT;
            float mt = fmaxf(v0, v1);
            #pragma unroll
            for (int o = 1; o < 16; o <<= 1) mt = fmaxf(mt, __shfl_xor(mt, o));
            float mold = s_m[h];
            float mnew = fmaxf(mold, mt);
            float p0 = __expf(v0 - mnew), p1 = __expf(v1 - mnew);
            float ls = p0 + p1;
            #pragma unroll
            for (int o = 1; o < 16; o <<= 1) ls += __shfl_xor(ls, o);
            s_S[h][k0] = p0; s_S[h][k0 + 1] = p1;
            if ((tid & 15) == 0) {
                float alpha = __expf(mold - mnew);
                s_alpha[h] = alpha;
                s_m[h] = mnew;
                s_l[h] = s_l[h] * alpha + ls;
            }
        }
        __syncthreads();

        f32x4 al4 = *(const f32x4*)&s_alpha[quad * 4];
        f32x4 p0v = *(const f32x4*)&s_S[l16][quad * 8];
        f32x4 p1v = *(const f32x4*)&s_S[l16][quad * 8 + 4];
        bf16x8 pf;
        pf[0] = (__bf16)p0v[0]; pf[1] = (__bf16)p0v[1];
        pf[2] = (__bf16)p0v[2]; pf[3] = (__bf16)p0v[3];
        pf[4] = (__bf16)p1v[0]; pf[5] = (__bf16)p1v[1];
        pf[6] = (__bf16)p1v[2]; pf[7] = (__bf16)p1v[3];
        const __bf16* sKb = (const __bf16*)sK;
        #pragma unroll
        for (int n = 0; n < 8; ++n) {
            int dim = wid * 128 + n * 16 + l16;
            bf16x8 vf;
            #pragma unroll
            for (int j = 0; j < 8; ++j)
                vf[j] = sKb[(quad * 8 + j) * SKS + dim];
            #pragma unroll
            for (int r = 0; r < 4; ++r) oacc[n][r] *= al4[r];
            oacc[n] = __builtin_amdgcn_mfma_f32_16x16x32_bf16(pf, vf, oacc[n], 0, 0, 0);
        }
        __syncthreads();
    }

    if (tid < 16) s_inv[tid] = 1.f / s_l[tid];
    __syncthreads();
    f32x4 inv4 = *(const f32x4*)&s_inv[quad * 4];
    #pragma unroll
    for (int n = 0; n < 8; ++n) {
        int dim = wid * 128 + n * 16 + l16;
        #pragma unroll
        for (int r = 0; r < 4; ++r) {
            int h = quad * 4 + r;
            o_lat[(size_t)q * 8192 + h * 512 + dim] = (__bf16)(oacc[n][r] * inv4[r]);
        }
    }
}

extern "C" void kernel_launch(void* const* d_in, const int* in_sizes, int n_in,
                              void* d_out, int out_size, void* d_ws, size_t ws_size,
                              hipStream_t stream) {
    const float* hid          = (const float*)d_in[0];
    const float* cosT         = (const float*)d_in[1];
    const float* sinT         = (const float*)d_in[2];
    const float* wq_a         = (const float*)d_in[3];
    const float* q_a_norm_w   = (const float*)d_in[4];
    const float* wq_b         = (const float*)d_in[5];
    const float* wkv_a        = (const float*)d_in[6];
    const float* kv_a_norm_w  = (const float*)d_in[7];
    const float* wkv_b        = (const float*)d_in[8];
    const float* wo           = (const float*)d_in[9];
    const float* idx_wq_b     = (const float*)d_in[10];
    const float* idx_wk       = (const float*)d_in[11];
    const float* idx_k_norm_w = (const float*)d_in[12];
    const float* idx_k_norm_b = (const float*)d_in[13];
    const float* idx_weights_w= (const float*)d_in[14];
    float* out = (float*)d_out;

    char* ws = (char*)d_ws;
    size_t off = 0;
    auto alloc = [&](size_t nbytes) {
        void* p = (void*)(ws + off);
        off += (nbytes + 255) & ~(size_t)255;
        return p;
    };
    float*  q_lora   = (float*) alloc((size_t)S_LEN * QLORA * 4);
    __bf16* qbuf_bf  = (__bf16*)alloc((size_t)S_LEN * NHEAD * QKHEAD * 2);
    float*  kv       = (float*) alloc((size_t)S_LEN * DLAT * 4);
    __bf16* klat_bf  = (__bf16*)alloc((size_t)S_LEN * DLAT * 2);
    __bf16* qeff_bf  = (__bf16*)alloc((size_t)S_LEN * NHEAD * DLAT * 2);
    int*    topk     = (int*)   alloc((size_t)S_LEN * TOPKN * 4);
    // union B: [hidH | wkv_a_bf] (early) / attn_o_bf (late, 8.4MB)
    char* uB = (char*)alloc((size_t)S_LEN * HIDDEN * 2 + (size_t)DLAT * HIDDEN * 2);
    __bf16* hidH      = (__bf16*)uB;
    __bf16* wkv_a_bf  = (__bf16*)(uB + (size_t)S_LEN * HIDDEN * 2);
    __bf16* attn_o_bf = (__bf16*)uB;
    __bf16* hidL      = (__bf16*)alloc((size_t)S_LEN * HIDDEN * 2);
    // union C: indexer block (early, 28.4MB) / o_lat (late, 33.6MB)
    char* uC = (char*)alloc((size_t)S_LEN * NHEAD * 512 * 2);
    __bf16* o_lat_bf = (__bf16*)uC;
    float* iqraw  = (float*)uC;
    float* ikraw  = (float*)(uC + 8388608);
    float* ikbuf  = (float*)(uC + 9437184);
    float* iwbuf  = (float*)(uC + 10485760);
    float* cqbuf  = (float*)(uC + 10551296);
    float* iscore = (float*)(uC + 11599872);
    __bf16* wq_b_bf  = (__bf16*)alloc((size_t)(NHEAD * QKHEAD) * QLORA * 2);
    __bf16* wkv_b_bf = (__bf16*)alloc((size_t)(NHEAD * 256) * KVLORA * 2);
    __bf16* wknt_bf  = (__bf16*)alloc((size_t)NHEAD * 512 * 128 * 2);
    __bf16* wo_bf    = (__bf16*)alloc((size_t)HIDDEN * (NHEAD * VDIM) * 2);
    // split hi/lo buffers for ~f32 MFMA GEMMs
    __bf16* wqaH = (__bf16*)alloc((size_t)QLORA * HIDDEN * 2);
    __bf16* wqaL = (__bf16*)alloc((size_t)QLORA * HIDDEN * 2);
    __bf16* qlH  = (__bf16*)alloc((size_t)S_LEN * QLORA * 2);
    __bf16* qlL  = (__bf16*)alloc((size_t)S_LEN * QLORA * 2);
    __bf16* iwqH = (__bf16*)alloc((size_t)(HIN * DIN) * QLORA * 2);
    __bf16* iwqL = (__bf16*)alloc((size_t)(HIN * DIN) * QLORA * 2);
    __bf16* iwkH = (__bf16*)alloc((size_t)DIN * HIDDEN * 2);
    __bf16* iwkL = (__bf16*)alloc((size_t)DIN * HIDDEN * 2);
    __bf16* ikH  = (__bf16*)alloc((size_t)S_LEN * DIN * 2);
    __bf16* ikL  = (__bf16*)alloc((size_t)S_LEN * DIN * 2);
    __bf16* cqH  = (__bf16*)alloc((size_t)S_LEN * DIN * 2);
    __bf16* cqL  = (__bf16*)alloc((size_t)S_LEN * DIN * 2);
    (void)ws_size; (void)in_sizes; (void)n_in; (void)out_size;

    dim3 blk(256);
    auto cst = [&](const float* src, __bf16* dst, int n) {
        cast4<<<(n / 4 + 255) / 256, blk, 0, stream>>>(src, dst, n);
    };
    auto spl = [&](const float* src, __bf16* h, __bf16* l, int n) {
        split4<<<(n / 4 + 255) / 256, blk, 0, stream>>>(src, h, l, n);
    };

    // casts / splits / weight transpose
    spl(hid,      hidH, hidL, S_LEN * HIDDEN);
    spl(wq_a,     wqaH, wqaL, QLORA * HIDDEN);
    spl(idx_wq_b, iwqH, iwqL, HIN * DIN * QLORA);
    spl(idx_wk,   iwkH, iwkL, DIN * HIDDEN);
    cst(wq_b,  wq_b_bf,  NHEAD * QKHEAD * QLORA);
    cst(wkv_a, wkv_a_bf, DLAT * HIDDEN);
    cst(wkv_b, wkv_b_bf, NHEAD * 256 * KVLORA);
    cst(wo,    wo_bf,    HIDDEN * NHEAD * VDIM);
    transpose_wkn<<<NHEAD * 512 * 128 / 256, blk, 0, stream>>>(wkv_b, wknt_bf);

    // q path: q_lora at ~f32 accuracy via split-bf16 MFMA
    gemm3<false><<<dim3(QLORA / GBN, S_LEN / GBM), blk, 0, stream>>>(
        hidH, hidL, wqaH, wqaL, q_lora, S_LEN, QLORA, HIDDEN, HIDDEN, HIDDEN, QLORA, 0);
    rmsnorm_rows<<<S_LEN, 256, 0, stream>>>(q_lora, q_a_norm_w, q_lora, QLORA);
    spl(q_lora, qlH, qlL, S_LEN * QLORA);         // qlH doubles as plain-bf16 q_lora
    gemm_s<__bf16><<<dim3((NHEAD * QKHEAD) / GBN, S_LEN / GBM, 1), blk, 0, stream>>>(
        qlH, wq_b_bf, qbuf_bf, S_LEN, NHEAD * QKHEAD, QLORA,
        QLORA, QLORA, NHEAD * QKHEAD, 0, 0, 0);
    rope_qeff<<<S_LEN, 256, 0, stream>>>(qbuf_bf, cosT, sinT, qeff_bf);
    gemm_s<__bf16><<<dim3(512 / GBN, S_LEN / GBM, NHEAD), blk, 0, stream>>>(
        qbuf_bf, wknt_bf, qeff_bf, S_LEN, 512, 128,
        NHEAD * QKHEAD, 128, NHEAD * DLAT, QKHEAD, 512 * 128, DLAT);
    // kv path -> Klat
    gemm_s<float><<<dim3(DLAT / GBN, S_LEN / GBM, 1), blk, 0, stream>>>(
        hidH, wkv_a_bf, kv, S_LEN, DLAT, HIDDEN, HIDDEN, HIDDEN, DLAT, 0, 0, 0);
    kv_post<<<S_LEN, 256, 0, stream>>>(kv, kv_a_norm_w, cosT, sinT, klat_bf);
    // indexer (~f32 via split-bf16; top-k set membership is precision-sensitive)
    gemm3<false><<<dim3((HIN * DIN) / GBN, S_LEN / GBM), blk, 0, stream>>>(
        qlH, qlL, iwqH, iwqL, iqraw, S_LEN, HIN * DIN, QLORA, QLORA, QLORA, HIN * DIN, 0);
    gemm3<false><<<dim3(DIN / GBN, S_LEN / GBM), blk, 0, stream>>>(
        hidH, hidL, iwkH, iwkL, ikraw, S_LEN, DIN, HIDDEN, HIDDEN, HIDDEN, DIN, 0);
    ik_post<<<S_LEN, 128, 0, stream>>>(ikraw, idx_k_norm_w, idx_k_norm_b, cosT, sinT, ikbuf);
    spl(ikbuf, ikH, ikL, S_LEN * DIN);
    iw_dots<<<S_LEN, 256, 0, stream>>>(hid, idx_weights_w, iwbuf);
    cq_kernel<<<S_LEN, 128, 0, stream>>>(iqraw, iwbuf, cosT, sinT, cqbuf);
    spl(cqbuf, cqH, cqL, S_LEN * DIN);
    // iscore: only rows >=512 (consumed by topk) and lower-triangle blocks
    gemm3<true><<<dim3(S_LEN / GBN, (S_LEN - TOPKN) / GBM), blk, 0, stream>>>(
        cqH, cqL, ikH, ikL, iscore, S_LEN, S_LEN, DIN, DIN, DIN, S_LEN, TOPKN);
    topk_rows<<<S_LEN - TOPKN, 256, 0, stream>>>(iscore, topk);
    // absorbed attention -> o_lat
    attn2<<<S_LEN, 256, 0, stream>>>(qeff_bf, klat_bf, topk, o_lat_bf);
    // V projection per head
    gemm_s<__bf16><<<dim3(VDIM / GBN, S_LEN / GBM, NHEAD), blk, 0, stream>>>(
        o_lat_bf, wkv_b_bf + 128 * 512, attn_o_bf, S_LEN, VDIM, 512,
        NHEAD * 512, 512, NHEAD * VDIM, 512, 256 * 512, VDIM);
    // output projection
    gemm_s<float><<<dim3(HIDDEN / GBN, S_LEN / GBM, 1), blk, 0, stream>>>(
        attn_o_bf, wo_bf, out, S_LEN, HIDDEN, NHEAD * VDIM,
        NHEAD * VDIM, NHEAD * VDIM, HIDDEN, 0, 0, 0);
}

// Round 5
// 669.488 us; speedup vs baseline: 7.2273x; 1.2752x over previous
//
#include <hip/hip_runtime.h>
#include <hip/hip_bf16.h>
#include <stdint.h>
#include <math.h>

#define S_LEN 2048
#define HIDDEN 2048
#define NHEAD 16
#define QLORA 768
#define KVLORA 512
#define QKNOPE 128
#define QKROPE 64
#define QKHEAD 192
#define VDIM 128
#define HIN 8
#define DIN 128
#define TOPKN 512
#define EPSF 1e-5f
#define DLAT 576           // 512 latent + 64 rope
#define SCALE_ATT 0.07216878364870322f  // 192^-0.5

typedef __bf16 bf16x8 __attribute__((ext_vector_type(8)));
typedef float  f32x4  __attribute__((ext_vector_type(4)));

static __device__ __forceinline__ float wave_reduce_sum(float v) {
    #pragma unroll
    for (int off = 32; off > 0; off >>= 1) v += __shfl_down(v, off);
    return v;
}

static __device__ __forceinline__ void splitw(__bf16* __restrict__ H,
                                              __bf16* __restrict__ L,
                                              size_t idx, float v) {
    __bf16 h = (__bf16)v;
    H[idx] = h;
    L[idx] = (__bf16)(v - (float)h);
}

// =============== fused prep: all casts / splits / transpose in ONE launch ===============
// region block counts (256 thr, 4 f32/thread => 1024 elems/block):
//  hid 4096 | wq_a 1536 | idx_wq_b 768 | idx_wk 256 | wq_b 2304 | wkv_a 1152
//  wkv_b 2048 | wo 4096 | wknt-transpose 1024   => 17280 blocks
#define PREP_BLOCKS 17280
__global__ __launch_bounds__(256) void prep_all(
        const float* __restrict__ hid,     __bf16* hidH,  __bf16* hidL,
        const float* __restrict__ wq_a,    __bf16* wqaH,  __bf16* wqaL,
        const float* __restrict__ idx_wq_b,__bf16* iwqH,  __bf16* iwqL,
        const float* __restrict__ idx_wk,  __bf16* iwkH,  __bf16* iwkL,
        const float* __restrict__ wq_b,    __bf16* wq_b_bf,
        const float* __restrict__ wkv_a,   __bf16* wkv_a_bf,
        const float* __restrict__ wkv_b,   __bf16* wkv_b_bf,
        const float* __restrict__ wo,      __bf16* wo_bf,
        __bf16* wknt) {
    int b = blockIdx.x, tid = threadIdx.x;
    const float* src; __bf16 *dH = nullptr, *dL = nullptr, *dC = nullptr;
    int base;
    if (b < 4096)        { src = hid;      dH = hidH; dL = hidL; base = b; }
    else if (b < 5632)   { src = wq_a;     dH = wqaH; dL = wqaL; base = b - 4096; }
    else if (b < 6400)   { src = idx_wq_b; dH = iwqH; dL = iwqL; base = b - 5632; }
    else if (b < 6656)   { src = idx_wk;   dH = iwkH; dL = iwkL; base = b - 6400; }
    else if (b < 8960)   { src = wq_b;     dC = wq_b_bf;  base = b - 6656; }
    else if (b < 10112)  { src = wkv_a;    dC = wkv_a_bf; base = b - 8960; }
    else if (b < 12160)  { src = wkv_b;    dC = wkv_b_bf; base = b - 10112; }
    else if (b < 16256)  { src = wo;       dC = wo_bf;    base = b - 12160; }
    else {
        // transpose wkv_b K-nope part: wknt[h][c][d] = wkv_b[(h*256+d)*512 + c]
        int e = ((b - 16256) * 256 + tid) * 4;
        int c = e & 511, d = (e >> 9) & 127, h = e >> 16;
        f32x4 v = *(const f32x4*)(wkv_b + ((size_t)(h * 256 + d)) * 512 + c);
        #pragma unroll
        for (int j = 0; j < 4; ++j)
            wknt[(size_t)h * 65536 + (c + j) * 128 + d] = (__bf16)v[j];
        return;
    }
    int i = (base * 256 + tid) * 4;
    f32x4 v = *(const f32x4*)(src + i);
    if (dC) {
        #pragma unroll
        for (int j = 0; j < 4; ++j) dC[i + j] = (__bf16)v[j];
    } else {
        #pragma unroll
        for (int j = 0; j < 4; ++j) splitw(dH, dL, i + j, v[j]);
    }
}

// ---------------- bf16 MFMA GEMM (strided, batched): C = A*B^T ----------------
#define GBM 128
#define GBN 64
#define GBK 32
template <typename OutT>
__global__ __launch_bounds__(256) void gemm_s(const __bf16* __restrict__ A,
                                              const __bf16* __restrict__ B,
                                              OutT* __restrict__ C,
                                              int M, int N, int K,
                                              int lda, int ldb, int ldc,
                                              long sA, long sB, long sC) {
    A += (size_t)blockIdx.z * sA;
    B += (size_t)blockIdx.z * sB;
    C += (size_t)blockIdx.z * sC;
    __shared__ __bf16 sAs[GBM * GBK];
    __shared__ __bf16 sBs[GBN * GBK];
    int tid = threadIdx.x;
    int lane = tid & 63, wid = tid >> 6;
    int quad = lane >> 4, l16 = lane & 15;
    int wm = wid >> 1, wn = wid & 1;
    int row0 = blockIdx.y * GBM, col0 = blockIdx.x * GBN;

    f32x4 acc[4][2] = {};
    int am = tid >> 1, ah = tid & 1;
    int bn = tid >> 2, bq = tid & 3;

    for (int k0 = 0; k0 < K; k0 += GBK) {
        const uint4* ga = (const uint4*)(A + (size_t)(row0 + am) * lda + k0 + ah * 16);
        uint4* da = (uint4*)&sAs[am * GBK + ah * 16];
        da[0] = ga[0];
        da[1] = ga[1];
        *(uint4*)&sBs[bn * GBK + bq * 8] =
            *(const uint4*)(B + (size_t)(col0 + bn) * ldb + k0 + bq * 8);
        __syncthreads();
        bf16x8 af[4], bfr[2];
        #pragma unroll
        for (int mi = 0; mi < 4; ++mi)
            af[mi] = *(const bf16x8*)&sAs[(wm * 64 + mi * 16 + l16) * GBK + quad * 8];
        #pragma unroll
        for (int ni = 0; ni < 2; ++ni)
            bfr[ni] = *(const bf16x8*)&sBs[(wn * 32 + ni * 16 + l16) * GBK + quad * 8];
        #pragma unroll
        for (int mi = 0; mi < 4; ++mi)
            #pragma unroll
            for (int ni = 0; ni < 2; ++ni)
                acc[mi][ni] = __builtin_amdgcn_mfma_f32_16x16x32_bf16(
                    af[mi], bfr[ni], acc[mi][ni], 0, 0, 0);
        __syncthreads();
    }
    #pragma unroll
    for (int mi = 0; mi < 4; ++mi)
        #pragma unroll
        for (int ni = 0; ni < 2; ++ni)
            #pragma unroll
            for (int r = 0; r < 4; ++r) {
                int row = row0 + wm * 64 + mi * 16 + quad * 4 + r;
                int col = col0 + wn * 32 + ni * 16 + l16;
                C[(size_t)row * ldc + col] = (OutT)acc[mi][ni][r];
            }
}

// ------------- split-bf16 (~f32 accuracy) MFMA GEMM: C = A*B^T -------------
template <bool CAUSAL>
__global__ __launch_bounds__(256) void gemm3(const __bf16* __restrict__ Ah,
                                             const __bf16* __restrict__ Al,
                                             const __bf16* __restrict__ Bh,
                                             const __bf16* __restrict__ Bl,
                                             float* __restrict__ C,
                                             int M, int N, int K,
                                             int lda, int ldb, int ldc,
                                             int row_base) {
    int row0 = blockIdx.y * GBM + row_base, col0 = blockIdx.x * GBN;
    if (CAUSAL && col0 > row0 + GBM - 1) return;
    __shared__ __bf16 sAh[GBM * GBK], sAl[GBM * GBK];
    __shared__ __bf16 sBh[GBN * GBK], sBl[GBN * GBK];
    int tid = threadIdx.x;
    int lane = tid & 63, wid = tid >> 6;
    int quad = lane >> 4, l16 = lane & 15;
    int wm = wid >> 1, wn = wid & 1;

    f32x4 acc[4][2] = {};
    int am = tid >> 1, ah = tid & 1;
    int bn = tid >> 2, bq = tid & 3;

    for (int k0 = 0; k0 < K; k0 += GBK) {
        size_t aoff = (size_t)(row0 + am) * lda + k0 + ah * 16;
        uint4* dah = (uint4*)&sAh[am * GBK + ah * 16];
        uint4* dal = (uint4*)&sAl[am * GBK + ah * 16];
        dah[0] = ((const uint4*)(Ah + aoff))[0];
        dah[1] = ((const uint4*)(Ah + aoff))[1];
        dal[0] = ((const uint4*)(Al + aoff))[0];
        dal[1] = ((const uint4*)(Al + aoff))[1];
        size_t boff = (size_t)(col0 + bn) * ldb + k0 + bq * 8;
        *(uint4*)&sBh[bn * GBK + bq * 8] = *(const uint4*)(Bh + boff);
        *(uint4*)&sBl[bn * GBK + bq * 8] = *(const uint4*)(Bl + boff);
        __syncthreads();
        bf16x8 afh[4], afl[4], bfh[2], bfl[2];
        #pragma unroll
        for (int mi = 0; mi < 4; ++mi) {
            int o = (wm * 64 + mi * 16 + l16) * GBK + quad * 8;
            afh[mi] = *(const bf16x8*)&sAh[o];
            afl[mi] = *(const bf16x8*)&sAl[o];
        }
        #pragma unroll
        for (int ni = 0; ni < 2; ++ni) {
            int o = (wn * 32 + ni * 16 + l16) * GBK + quad * 8;
            bfh[ni] = *(const bf16x8*)&sBh[o];
            bfl[ni] = *(const bf16x8*)&sBl[o];
        }
        #pragma unroll
        for (int mi = 0; mi < 4; ++mi)
            #pragma unroll
            for (int ni = 0; ni < 2; ++ni) {
                acc[mi][ni] = __builtin_amdgcn_mfma_f32_16x16x32_bf16(
                    afl[mi], bfh[ni], acc[mi][ni], 0, 0, 0);
                acc[mi][ni] = __builtin_amdgcn_mfma_f32_16x16x32_bf16(
                    afh[mi], bfl[ni], acc[mi][ni], 0, 0, 0);
                acc[mi][ni] = __builtin_amdgcn_mfma_f32_16x16x32_bf16(
                    afh[mi], bfh[ni], acc[mi][ni], 0, 0, 0);
            }
        __syncthreads();
    }
    #pragma unroll
    for (int mi = 0; mi < 4; ++mi)
        #pragma unroll
        for (int ni = 0; ni < 2; ++ni)
            #pragma unroll
            for (int r = 0; r < 4; ++r) {
                int row = row0 + wm * 64 + mi * 16 + quad * 4 + r;
                int col = col0 + wn * 32 + ni * 16 + l16;
                C[(size_t)row * ldc + col] = acc[mi][ni][r];
            }
}

// ---------------- RMSNorm rows -> split hi/lo bf16 directly ----------------
__global__ __launch_bounds__(256) void rmsnorm_split(const float* __restrict__ x,
                                                     const float* __restrict__ w,
                                                     __bf16* __restrict__ yH,
                                                     __bf16* __restrict__ yL, int ncols) {
    int row = blockIdx.x, tid = threadIdx.x;
    const float* xr = x + (size_t)row * ncols;
    float ss = 0.f;
    for (int c = tid; c < ncols; c += 256) { float v = xr[c]; ss += v * v; }
    __shared__ float red[4];
    ss = wave_reduce_sum(ss);
    if ((tid & 63) == 0) red[tid >> 6] = ss;
    __syncthreads();
    float tot = red[0] + red[1] + red[2] + red[3];
    float inv = rsqrtf(tot / (float)ncols + EPSF);
    for (int c = tid; c < ncols; c += 256)
        splitw(yH, yL, (size_t)row * ncols + c, xr[c] * inv * w[c]);
}

// ---------------- rope q (bf16 in), write into Qeff[...,512:576] ----------------
__global__ __launch_bounds__(256) void rope_qeff(const __bf16* __restrict__ qbuf,
                                                 const float* __restrict__ cosT,
                                                 const float* __restrict__ sinT,
                                                 __bf16* __restrict__ qeff) {
    int s = blockIdx.x;
    for (int i = threadIdx.x; i < NHEAD * 32; i += 256) {
        int h = i >> 5, d = i & 31;
        const __bf16* base = qbuf + (size_t)s * (NHEAD * QKHEAD) + h * QKHEAD + QKNOPE;
        float x1 = (float)base[d], x2 = (float)base[d + 32];
        float c1 = cosT[s * 64 + d],      s1 = sinT[s * 64 + d];
        float c2 = cosT[s * 64 + d + 32], s2 = sinT[s * 64 + d + 32];
        __bf16* o = qeff + (size_t)s * (NHEAD * DLAT) + h * DLAT + 512;
        o[d]      = (__bf16)(x1 * c1 - x2 * s1);
        o[d + 32] = (__bf16)(x2 * c2 + x1 * s2);
    }
}

// ---------------- kv post: rmsnorm 512 + rope 64 -> Klat[2048,576] bf16 ---------------
__global__ __launch_bounds__(256) void kv_post(const float* __restrict__ kv,
                                               const float* __restrict__ kvw,
                                               const float* __restrict__ cosT,
                                               const float* __restrict__ sinT,
                                               __bf16* __restrict__ klat) {
    int s = blockIdx.x, tid = threadIdx.x;
    const float* row = kv + (size_t)s * DLAT;
    float ss = 0.f;
    for (int c = tid; c < KVLORA; c += 256) { float v = row[c]; ss += v * v; }
    __shared__ float red[4];
    ss = wave_reduce_sum(ss);
    if ((tid & 63) == 0) red[tid >> 6] = ss;
    __syncthreads();
    float tot = red[0] + red[1] + red[2] + red[3];
    float inv = rsqrtf(tot / (float)KVLORA + EPSF);
    __bf16* orow = klat + (size_t)s * DLAT;
    for (int c = tid; c < KVLORA; c += 256)
        orow[c] = (__bf16)(row[c] * inv * kvw[c]);
    if (tid < 32) {
        int d = tid;
        float x1 = row[KVLORA + d], x2 = row[KVLORA + d + 32];
        float c1 = cosT[s * 64 + d],      s1 = sinT[s * 64 + d];
        float c2 = cosT[s * 64 + d + 32], s2 = sinT[s * 64 + d + 32];
        orow[512 + d]      = (__bf16)(x1 * c1 - x2 * s1);
        orow[512 + d + 32] = (__bf16)(x2 * c2 + x1 * s2);
    }
}

// -------- ik post: layer_norm(128) + rope first 64, split hi/lo out (f32 math) --------
__global__ __launch_bounds__(128) void ik_post_split(const float* __restrict__ ikraw,
                                                     const float* __restrict__ w,
                                                     const float* __restrict__ b,
                                                     const float* __restrict__ cosT,
                                                     const float* __restrict__ sinT,
                                                     __bf16* __restrict__ ikH,
                                                     __bf16* __restrict__ ikL) {
    int s = blockIdx.x, tid = threadIdx.x;
    float x = ikraw[(size_t)s * DIN + tid];
    __shared__ float redA[2], redB[2], sy[DIN];
    float sm = wave_reduce_sum(x);
    if ((tid & 63) == 0) redA[tid >> 6] = sm;
    __syncthreads();
    float mean = (redA[0] + redA[1]) / (float)DIN;
    float dx = x - mean;
    float vs = wave_reduce_sum(dx * dx);
    if ((tid & 63) == 0) redB[tid >> 6] = vs;
    __syncthreads();
    float var = (redB[0] + redB[1]) / (float)DIN;
    sy[tid] = dx * rsqrtf(var + EPSF) * w[tid] + b[tid];
    __syncthreads();
    size_t ro = (size_t)s * DIN;
    if (tid < 32) {
        int d = tid;
        float c1 = cosT[s * 64 + d],      s1 = sinT[s * 64 + d];
        float c2 = cosT[s * 64 + d + 32], s2 = sinT[s * 64 + d + 32];
        splitw(ikH, ikL, ro + d,      sy[d] * c1 - sy[d + 32] * s1);
        splitw(ikH, ikL, ro + d + 32, sy[d + 32] * c2 + sy[d] * s2);
    } else if (tid >= 64) {
        splitw(ikH, ikL, ro + tid, sy[tid]);
    }
}

// ------- cq: compute iw dots in-block, fold into roped iq, split hi/lo out -------
__global__ __launch_bounds__(128) void cq2(const float* __restrict__ iqraw,
                                           const float* __restrict__ hid,
                                           const float* __restrict__ iww,
                                           const float* __restrict__ cosT,
                                           const float* __restrict__ sinT,
                                           __bf16* __restrict__ cqH,
                                           __bf16* __restrict__ cqL) {
    int s = blockIdx.x, tid = threadIdx.x;
    int lane = tid & 63, wid = tid >> 6;
    __shared__ float red[2][HIN], siw[HIN];
    // iw[h] = hid[s,:] . iww[h,:]
    float a8[HIN] = {};
    const float* xr = hid + (size_t)s * HIDDEN;
    for (int c = tid; c < HIDDEN; c += 128) {
        float x = xr[c];
        #pragma unroll
        for (int h = 0; h < HIN; ++h) a8[h] += x * iww[h * HIDDEN + c];
    }
    #pragma unroll
    for (int h = 0; h < HIN; ++h) a8[h] = wave_reduce_sum(a8[h]);
    if (lane == 0)
        #pragma unroll
        for (int h = 0; h < HIN; ++h) red[wid][h] = a8[h];
    __syncthreads();
    if (tid < HIN) siw[tid] = red[0][tid] + red[1][tid];
    __syncthreads();
    int d = tid;
    float acc = 0.f;
    float c1 = 0.f, s1 = 0.f;
    if (d < 64) { c1 = cosT[s * 64 + d]; s1 = sinT[s * 64 + d]; }
    #pragma unroll
    for (int h = 0; h < HIN; ++h) {
        const float* base = iqraw + ((size_t)s * HIN + h) * DIN;
        float v;
        if (d < 32)       v = base[d] * c1 - base[d + 32] * s1;
        else if (d < 64)  v = base[d] * c1 + base[d - 32] * s1;
        else              v = base[d];
        acc += siw[h] * v;
    }
    splitw(cqH, cqL, (size_t)s * DIN + d, acc * 0.03125f);
}

// ------------- exact top-512 per row (rows q >= 512), parallel radix select -------------
__global__ __launch_bounds__(256) void topk_rows(const float* __restrict__ iscore,
                                                 int* __restrict__ topk) {
    int q = TOPKN + blockIdx.x;
    int n = q + 1;
    __shared__ uint32_t skey[S_LEN];
    __shared__ int hist[256];
    __shared__ int scan[256];
    __shared__ uint32_t sp;
    __shared__ int sr, pos;
    int tid = threadIdx.x;
    const float* row = iscore + (size_t)q * S_LEN;
    for (int i = tid; i < n; i += 256) {
        uint32_t u = __float_as_uint(row[i]);
        skey[i] = (u & 0x80000000u) ? ~u : (u | 0x80000000u);
    }
    __syncthreads();
    uint32_t prefix = 0;
    int remk = TOPKN;
    for (int pass = 0; pass < 4; ++pass) {
        int shift = 24 - 8 * pass;
        uint32_t pmask = pass ? (0xFFFFFFFFu << (shift + 8)) : 0u;
        hist[tid] = 0;
        __syncthreads();
        for (int i = tid; i < n; i += 256) {
            uint32_t u = skey[i];
            if ((u & pmask) == prefix) atomicAdd(&hist[(u >> shift) & 255], 1);
        }
        __syncthreads();
        // suffix sum: scan[b] = sum_{b'>=b} hist[b']
        scan[tid] = hist[tid];
        __syncthreads();
        for (int step = 1; step < 256; step <<= 1) {
            int v = (tid + step < 256) ? scan[tid + step] : 0;
            __syncthreads();
            scan[tid] += v;
            __syncthreads();
        }
        int Sb = scan[tid];
        int Snext = (tid < 255) ? scan[tid + 1] : 0;
        if (Sb >= remk && Snext < remk) {
            sp = prefix | ((uint32_t)tid << shift);
            sr = remk - Snext;
        }
        __syncthreads();
        prefix = sp; remk = sr;
        __syncthreads();
    }
    if (tid == 0) pos = 0;
    __syncthreads();
    int* orow = topk + (size_t)q * TOPKN;
    for (int i = tid; i < n; i += 256) {
        if (skey[i] > prefix) { int p = atomicAdd(&pos, 1); orow[p] = i; }
    }
    __syncthreads();
    int base = pos;   // == TOPKN - remk
    // ties: take the remk smallest-index equal keys (lax.top_k semantics), in parallel.
    int chunk = (n + 255) >> 8;
    int lo = tid * chunk, hiEnd = lo + chunk;
    if (hiEnd > n) hiEnd = n;
    int cnt = 0;
    for (int i = lo; i < hiEnd; ++i) cnt += (skey[i] == prefix);
    scan[tid] = cnt;
    __syncthreads();
    for (int step = 1; step < 256; step <<= 1) {
        int v = (tid >= step) ? scan[tid - step] : 0;
        __syncthreads();
        scan[tid] += v;
        __syncthreads();
    }
    int r = scan[tid] - cnt;   // exclusive prefix (index-major == thread-major)
    for (int i = lo; i < hiEnd && r < remk; ++i) {
        if (skey[i] == prefix) { orow[base + r] = i; ++r; }
    }
}

// ---------------- absorbed-MLA flash attention: one workgroup per q --------------
// k-slot permutation j -> j^quad applied identically to P and V fragments:
// MFMA contraction is a per-quad sum, so this is bit-identical math but makes the
// PV scalar LDS reads <=2-way bank-aliased (free) instead of 4-way.
#define SKS 584   // shorts per sK row (1168 B, 16B-aligned pitch)
__global__ __launch_bounds__(256) void attn2(const __bf16* __restrict__ qeff,
                                             const __bf16* __restrict__ klat,
                                             const int* __restrict__ topk,
                                             __bf16* __restrict__ o_lat) {
    int q = blockIdx.x;
    int tid = threadIdx.x;
    int lane = tid & 63, wid = tid >> 6;
    int l16 = lane & 15, quad = lane >> 4;
    int wn = wid & 1, wk = wid >> 1;

    __shared__ short sK[32 * SKS];
    __shared__ float s_part[2][16][37];
    __shared__ float s_S[16][37];
    __shared__ float s_m[16], s_l[16], s_alpha[16], s_inv[16];

    int L = (q < TOPKN) ? (q + 1) : TOPKN;
    int nt = (L + 31) >> 5;
    const int* idxr = topk + (size_t)q * TOPKN;

    bf16x8 qf[9];
    const __bf16* qrow = qeff + (size_t)q * (NHEAD * DLAT) + l16 * DLAT + wk * 288 + quad * 8;
    #pragma unroll
    for (int s = 0; s < 9; ++s) qf[s] = *(const bf16x8*)(qrow + s * 32);

    if (tid < 16) { s_m[tid] = -1e30f; s_l[tid] = 0.f; }

    f32x4 oacc[8];
    #pragma unroll
    for (int i = 0; i < 8; ++i) oacc[i] = (f32x4){0.f, 0.f, 0.f, 0.f};

    int srow = tid >> 3, schk = tid & 7;

    for (int t = 0; t < nt; ++t) {
        int ki = t * 32 + srow;
        int gk = 0;
        if (ki < L) gk = (q < TOPKN) ? ki : idxr[ki];
        const uint4* src = (const uint4*)(klat + (size_t)gk * DLAT) + schk * 9;
        uint4* dst = (uint4*)((char*)sK + srow * (SKS * 2) + schk * 144);
        #pragma unroll
        for (int c = 0; c < 9; ++c) dst[c] = src[c];
        __syncthreads();

        f32x4 sacc = {0.f, 0.f, 0.f, 0.f};
        const short* kbase = sK + (wn * 16 + l16) * SKS + wk * 288 + quad * 8;
        #pragma unroll
        for (int s = 0; s < 9; ++s) {
            bf16x8 kf = *(const bf16x8*)(kbase + s * 32);
            sacc = __builtin_amdgcn_mfma_f32_16x16x32_bf16(qf[s], kf, sacc, 0, 0, 0);
        }
        #pragma unroll
        for (int r = 0; r < 4; ++r)
            s_part[wk][quad * 4 + r][wn * 16 + l16] = sacc[r];
        __syncthreads();

        {
            int h = tid >> 4, k0 = (tid & 15) * 2;
            float v0 = -1e30f, v1 = -1e30f;
            if (t * 32 + k0 < L)
                v0 = (s_part[0][h][k0] + s_part[1][h][k0]) * SCALE_ATT;
            if (t * 32 + k0 + 1 < L)
                v1 = (s_part[0][h][k0 + 1] + s_part[1][h][k0 + 1]) * SCALE_ATT;
            float mt = fmaxf(v0, v1);
            #pragma unroll
            for (int o = 1; o < 16; o <<= 1) mt = fmaxf(mt, __shfl_xor(mt, o));
            float mold = s_m[h];
            float mnew = fmaxf(mold, mt);
            float p0 = __expf(v0 - mnew), p1 = __expf(v1 - mnew);
            float ls = p0 + p1;
            #pragma unroll
            for (int o = 1; o < 16; o <<= 1) ls += __shfl_xor(ls, o);
            s_S[h][k0] = p0; s_S[h][k0 + 1] = p1;
            if ((tid & 15) == 0) {
                float alpha = __expf(mold - mnew);
                s_alpha[h] = alpha;
                s_m[h] = mnew;
                s_l[h] = s_l[h] * alpha + ls;
            }
        }
        __syncthreads();

        f32x4 al4 = *(const f32x4*)&s_alpha[quad * 4];
        // A-frag (P) with k-slot permutation j -> j^quad
        bf16x8 pf;
        #pragma unroll
        for (int j = 0; j < 8; ++j)
            pf[j] = (__bf16)s_S[l16][quad * 8 + (j ^ quad)];
        const __bf16* sKb = (const __bf16*)sK;
        #pragma unroll
        for (int n = 0; n < 8; ++n) {
            int dim = wid * 128 + n * 16 + l16;
            bf16x8 vf;
            #pragma unroll
            for (int j = 0; j < 8; ++j)
                vf[j] = sKb[(quad * 8 + (j ^ quad)) * SKS + dim];
            #pragma unroll
            for (int r = 0; r < 4; ++r) oacc[n][r] *= al4[r];
            oacc[n] = __builtin_amdgcn_mfma_f32_16x16x32_bf16(pf, vf, oacc[n], 0, 0, 0);
        }
        __syncthreads();
    }

    if (tid < 16) s_inv[tid] = 1.f / s_l[tid];
    __syncthreads();
    f32x4 inv4 = *(const f32x4*)&s_inv[quad * 4];
    #pragma unroll
    for (int n = 0; n < 8; ++n) {
        int dim = wid * 128 + n * 16 + l16;
        #pragma unroll
        for (int r = 0; r < 4; ++r) {
            int h = quad * 4 + r;
            o_lat[(size_t)q * 8192 + h * 512 + dim] = (__bf16)(oacc[n][r] * inv4[r]);
        }
    }
}

extern "C" void kernel_launch(void* const* d_in, const int* in_sizes, int n_in,
                              void* d_out, int out_size, void* d_ws, size_t ws_size,
                              hipStream_t stream) {
    const float* hid          = (const float*)d_in[0];
    const float* cosT         = (const float*)d_in[1];
    const float* sinT         = (const float*)d_in[2];
    const float* wq_a         = (const float*)d_in[3];
    const float* q_a_norm_w   = (const float*)d_in[4];
    const float* wq_b         = (const float*)d_in[5];
    const float* wkv_a        = (const float*)d_in[6];
    const float* kv_a_norm_w  = (const float*)d_in[7];
    const float* wkv_b        = (const float*)d_in[8];
    const float* wo           = (const float*)d_in[9];
    const float* idx_wq_b     = (const float*)d_in[10];
    const float* idx_wk       = (const float*)d_in[11];
    const float* idx_k_norm_w = (const float*)d_in[12];
    const float* idx_k_norm_b = (const float*)d_in[13];
    const float* idx_weights_w= (const float*)d_in[14];
    float* out = (float*)d_out;

    char* ws = (char*)d_ws;
    size_t off = 0;
    auto alloc = [&](size_t nbytes) {
        void* p = (void*)(ws + off);
        off += (nbytes + 255) & ~(size_t)255;
        return p;
    };
    float*  q_lora   = (float*) alloc((size_t)S_LEN * QLORA * 4);
    __bf16* qbuf_bf  = (__bf16*)alloc((size_t)S_LEN * NHEAD * QKHEAD * 2);
    float*  kv       = (float*) alloc((size_t)S_LEN * DLAT * 4);
    __bf16* klat_bf  = (__bf16*)alloc((size_t)S_LEN * DLAT * 2);
    __bf16* qeff_bf  = (__bf16*)alloc((size_t)S_LEN * NHEAD * DLAT * 2);
    int*    topk     = (int*)   alloc((size_t)S_LEN * TOPKN * 4);
    // union B: [hidH | wkv_a_bf] (early) / attn_o_bf (late, 8.4MB)
    char* uB = (char*)alloc((size_t)S_LEN * HIDDEN * 2 + (size_t)DLAT * HIDDEN * 2);
    __bf16* hidH      = (__bf16*)uB;
    __bf16* wkv_a_bf  = (__bf16*)(uB + (size_t)S_LEN * HIDDEN * 2);
    __bf16* attn_o_bf = (__bf16*)uB;
    __bf16* hidL      = (__bf16*)alloc((size_t)S_LEN * HIDDEN * 2);
    // union C: indexer block (early, 28.4MB) / o_lat (late, 33.6MB)
    char* uC = (char*)alloc((size_t)S_LEN * NHEAD * 512 * 2);
    __bf16* o_lat_bf = (__bf16*)uC;
    float* iqraw  = (float*)uC;
    float* ikraw  = (float*)(uC + 8388608);
    float* iscore = (float*)(uC + 11599872);
    __bf16* wq_b_bf  = (__bf16*)alloc((size_t)(NHEAD * QKHEAD) * QLORA * 2);
    __bf16* wkv_b_bf = (__bf16*)alloc((size_t)(NHEAD * 256) * KVLORA * 2);
    __bf16* wknt_bf  = (__bf16*)alloc((size_t)NHEAD * 512 * 128 * 2);
    __bf16* wo_bf    = (__bf16*)alloc((size_t)HIDDEN * (NHEAD * VDIM) * 2);
    __bf16* wqaH = (__bf16*)alloc((size_t)QLORA * HIDDEN * 2);
    __bf16* wqaL = (__bf16*)alloc((size_t)QLORA * HIDDEN * 2);
    __bf16* qlH  = (__bf16*)alloc((size_t)S_LEN * QLORA * 2);
    __bf16* qlL  = (__bf16*)alloc((size_t)S_LEN * QLORA * 2);
    __bf16* iwqH = (__bf16*)alloc((size_t)(HIN * DIN) * QLORA * 2);
    __bf16* iwqL = (__bf16*)alloc((size_t)(HIN * DIN) * QLORA * 2);
    __bf16* iwkH = (__bf16*)alloc((size_t)DIN * HIDDEN * 2);
    __bf16* iwkL = (__bf16*)alloc((size_t)DIN * HIDDEN * 2);
    __bf16* ikH  = (__bf16*)alloc((size_t)S_LEN * DIN * 2);
    __bf16* ikL  = (__bf16*)alloc((size_t)S_LEN * DIN * 2);
    __bf16* cqH  = (__bf16*)alloc((size_t)S_LEN * DIN * 2);
    __bf16* cqL  = (__bf16*)alloc((size_t)S_LEN * DIN * 2);
    (void)ws_size; (void)in_sizes; (void)n_in; (void)out_size;

    dim3 blk(256);

    // 1. all casts / splits / transpose in one launch
    prep_all<<<PREP_BLOCKS, blk, 0, stream>>>(
        hid, hidH, hidL, wq_a, wqaH, wqaL, idx_wq_b, iwqH, iwqL,
        idx_wk, iwkH, iwkL, wq_b, wq_b_bf, wkv_a, wkv_a_bf,
        wkv_b, wkv_b_bf, wo, wo_bf, wknt_bf);

    // q path: q_lora at ~f32 accuracy via split-bf16 MFMA
    gemm3<false><<<dim3(QLORA / GBN, S_LEN / GBM), blk, 0, stream>>>(
        hidH, hidL, wqaH, wqaL, q_lora, S_LEN, QLORA, HIDDEN, HIDDEN, HIDDEN, QLORA, 0);
    rmsnorm_split<<<S_LEN, 256, 0, stream>>>(q_lora, q_a_norm_w, qlH, qlL, QLORA);
    gemm_s<__bf16><<<dim3((NHEAD * QKHEAD) / GBN, S_LEN / GBM, 1), blk, 0, stream>>>(
        qlH, wq_b_bf, qbuf_bf, S_LEN, NHEAD * QKHEAD, QLORA,
        QLORA, QLORA, NHEAD * QKHEAD, 0, 0, 0);
    rope_qeff<<<S_LEN, 256, 0, stream>>>(qbuf_bf, cosT, sinT, qeff_bf);
    gemm_s<__bf16><<<dim3(512 / GBN, S_LEN / GBM, NHEAD), blk, 0, stream>>>(
        qbuf_bf, wknt_bf, qeff_bf, S_LEN, 512, 128,
        NHEAD * QKHEAD, 128, NHEAD * DLAT, QKHEAD, 512 * 128, DLAT);
    // kv path -> Klat
    gemm_s<float><<<dim3(DLAT / GBN, S_LEN / GBM, 1), blk, 0, stream>>>(
        hidH, wkv_a_bf, kv, S_LEN, DLAT, HIDDEN, HIDDEN, HIDDEN, DLAT, 0, 0, 0);
    kv_post<<<S_LEN, 256, 0, stream>>>(kv, kv_a_norm_w, cosT, sinT, klat_bf);
    // indexer (~f32 via split-bf16; top-k set membership is precision-sensitive)
    gemm3<false><<<dim3((HIN * DIN) / GBN, S_LEN / GBM), blk, 0, stream>>>(
        qlH, qlL, iwqH, iwqL, iqraw, S_LEN, HIN * DIN, QLORA, QLORA, QLORA, HIN * DIN, 0);
    gemm3<false><<<dim3(DIN / GBN, S_LEN / GBM), blk, 0, stream>>>(
        hidH, hidL, iwkH, iwkL, ikraw, S_LEN, DIN, HIDDEN, HIDDEN, HIDDEN, DIN, 0);
    ik_post_split<<<S_LEN, 128, 0, stream>>>(ikraw, idx_k_norm_w, idx_k_norm_b,
                                             cosT, sinT, ikH, ikL);
    cq2<<<S_LEN, 128, 0, stream>>>(iqraw, hid, idx_weights_w, cosT, sinT, cqH, cqL);
    // iscore: only rows >=512 (consumed by topk) and lower-triangle blocks
    gemm3<true><<<dim3(S_LEN / GBN, (S_LEN - TOPKN) / GBM), blk, 0, stream>>>(
        cqH, cqL, ikH, ikL, iscore, S_LEN, S_LEN, DIN, DIN, DIN, S_LEN, TOPKN);
    topk_rows<<<S_LEN - TOPKN, 256, 0, stream>>>(iscore, topk);
    // absorbed attention -> o_lat
    attn2<<<S_LEN, 256, 0, stream>>>(qeff_bf, klat_bf, topk, o_lat_bf);
    // V projection per head
    gemm_s<__bf16><<<dim3(VDIM / GBN, S_LEN / GBM, NHEAD), blk, 0, stream>>>(
        o_lat_bf, wkv_b_bf + 128 * 512, attn_o_bf, S_LEN, VDIM, 512,
        NHEAD * 512, 512, NHEAD * VDIM, 512, 256 * 512, VDIM);
    // output projection
    gemm_s<float><<<dim3(HIDDEN / GBN, S_LEN / GBM, 1), blk, 0, stream>>>(
        attn_o_bf, wo_bf, out, S_LEN, HIDDEN, NHEAD * VDIM,
        NHEAD * VDIM, NHEAD * VDIM, HIDDEN, 0, 0, 0);
}

// Round 7
// 572.629 us; speedup vs baseline: 8.4498x; 1.1691x over previous
//
#include <hip/hip_runtime.h>
#include <hip/hip_bf16.h>
#include <stdint.h>
#include <math.h>

#define S_LEN 2048
#define HIDDEN 2048
#define NHEAD 16
#define QLORA 768
#define KVLORA 512
#define QKNOPE 128
#define QKROPE 64
#define QKHEAD 192
#define VDIM 128
#define HIN 8
#define DIN 128
#define TOPKN 512
#define EPSF 1e-5f
#define DLAT 576
#define SCALE_ATT 0.07216878364870322f  // 192^-0.5

typedef __bf16 bf16x8 __attribute__((ext_vector_type(8)));
typedef float  f32x4  __attribute__((ext_vector_type(4)));

static __device__ __forceinline__ float wave_reduce_sum(float v) {
    #pragma unroll
    for (int off = 32; off > 0; off >>= 1) v += __shfl_down(v, off);
    return v;
}

static __device__ __forceinline__ void splitw(__bf16* __restrict__ H,
                                              __bf16* __restrict__ L,
                                              size_t idx, float v) {
    __bf16 h = (__bf16)v;
    H[idx] = h;
    L[idx] = (__bf16)(v - (float)h);
}

// =============== fused prep: all casts / splits / transpose in ONE launch ===============
#define PREP_BLOCKS 17280
__global__ __launch_bounds__(256) void prep_all(
        const float* __restrict__ hid,     __bf16* hidH,  __bf16* hidL,
        const float* __restrict__ wq_a,    __bf16* wqaH,  __bf16* wqaL,
        const float* __restrict__ idx_wq_b,__bf16* iwqH,  __bf16* iwqL,
        const float* __restrict__ idx_wk,  __bf16* iwkH,  __bf16* iwkL,
        const float* __restrict__ wq_b,    __bf16* wq_b_bf,
        const float* __restrict__ wkv_a,   __bf16* wkv_a_bf,
        const float* __restrict__ wkv_b,   __bf16* wkv_b_bf,
        const float* __restrict__ wo,      __bf16* wo_bf,
        __bf16* wknt) {
    int b = blockIdx.x, tid = threadIdx.x;
    const float* src; __bf16 *dH = nullptr, *dL = nullptr, *dC = nullptr;
    int base;
    if (b < 4096)        { src = hid;      dH = hidH; dL = hidL; base = b; }
    else if (b < 5632)   { src = wq_a;     dH = wqaH; dL = wqaL; base = b - 4096; }
    else if (b < 6400)   { src = idx_wq_b; dH = iwqH; dL = iwqL; base = b - 5632; }
    else if (b < 6656)   { src = idx_wk;   dH = iwkH; dL = iwkL; base = b - 6400; }
    else if (b < 8960)   { src = wq_b;     dC = wq_b_bf;  base = b - 6656; }
    else if (b < 10112)  { src = wkv_a;    dC = wkv_a_bf; base = b - 8960; }
    else if (b < 12160)  { src = wkv_b;    dC = wkv_b_bf; base = b - 10112; }
    else if (b < 16256)  { src = wo;       dC = wo_bf;    base = b - 12160; }
    else {
        int e = ((b - 16256) * 256 + tid) * 4;
        int c = e & 511, d = (e >> 9) & 127, h = e >> 16;
        f32x4 v = *(const f32x4*)(wkv_b + ((size_t)(h * 256 + d)) * 512 + c);
        #pragma unroll
        for (int j = 0; j < 4; ++j)
            wknt[(size_t)h * 65536 + (c + j) * 128 + d] = (__bf16)v[j];
        return;
    }
    int i = (base * 256 + tid) * 4;
    f32x4 v = *(const f32x4*)(src + i);
    if (dC) {
        #pragma unroll
        for (int j = 0; j < 4; ++j) dC[i + j] = (__bf16)v[j];
    } else {
        #pragma unroll
        for (int j = 0; j < 4; ++j) splitw(dH, dL, i + j, v[j]);
    }
}

// ---------------- bf16 MFMA GEMM core: C = A*B^T ----------------
#define GBM 128
#define GBN 64
#define GBK 32
template <typename OutT>
static __device__ __forceinline__ void gemm_s_core(
        const __bf16* __restrict__ A, const __bf16* __restrict__ B,
        OutT* __restrict__ C, int K, int lda, int ldb, int ldc,
        int bx, int by) {
    __shared__ __bf16 sAs[GBM * GBK];
    __shared__ __bf16 sBs[GBN * GBK];
    int tid = threadIdx.x;
    int lane = tid & 63, wid = tid >> 6;
    int quad = lane >> 4, l16 = lane & 15;
    int wm = wid >> 1, wn = wid & 1;
    int row0 = by * GBM, col0 = bx * GBN;

    f32x4 acc[4][2] = {};
    int am = tid >> 1, ah = tid & 1;
    int bn = tid >> 2, bq = tid & 3;

    for (int k0 = 0; k0 < K; k0 += GBK) {
        const uint4* ga = (const uint4*)(A + (size_t)(row0 + am) * lda + k0 + ah * 16);
        uint4* da = (uint4*)&sAs[am * GBK + ah * 16];
        da[0] = ga[0];
        da[1] = ga[1];
        *(uint4*)&sBs[bn * GBK + bq * 8] =
            *(const uint4*)(B + (size_t)(col0 + bn) * ldb + k0 + bq * 8);
        __syncthreads();
        bf16x8 af[4], bfr[2];
        #pragma unroll
        for (int mi = 0; mi < 4; ++mi)
            af[mi] = *(const bf16x8*)&sAs[(wm * 64 + mi * 16 + l16) * GBK + quad * 8];
        #pragma unroll
        for (int ni = 0; ni < 2; ++ni)
            bfr[ni] = *(const bf16x8*)&sBs[(wn * 32 + ni * 16 + l16) * GBK + quad * 8];
        #pragma unroll
        for (int mi = 0; mi < 4; ++mi)
            #pragma unroll
            for (int ni = 0; ni < 2; ++ni)
                acc[mi][ni] = __builtin_amdgcn_mfma_f32_16x16x32_bf16(
                    af[mi], bfr[ni], acc[mi][ni], 0, 0, 0);
        __syncthreads();
    }
    #pragma unroll
    for (int mi = 0; mi < 4; ++mi)
        #pragma unroll
        for (int ni = 0; ni < 2; ++ni)
            #pragma unroll
            for (int r = 0; r < 4; ++r) {
                int row = row0 + wm * 64 + mi * 16 + quad * 4 + r;
                int col = col0 + wn * 32 + ni * 16 + l16;
                C[(size_t)row * ldc + col] = (OutT)acc[mi][ni][r];
            }
}

template <typename OutT>
__global__ __launch_bounds__(256) void gemm_s(const __bf16* __restrict__ A,
                                              const __bf16* __restrict__ B,
                                              OutT* __restrict__ C,
                                              int K, int lda, int ldb, int ldc,
                                              long sA, long sB, long sC) {
    gemm_s_core<OutT>(A + (size_t)blockIdx.z * sA, B + (size_t)blockIdx.z * sB,
                      C + (size_t)blockIdx.z * sC, K, lda, ldb, ldc,
                      blockIdx.x, blockIdx.y);
}

// ------------- split-bf16 (~f32) MFMA GEMM core: C = Ah*Bh + Ah*Bl + Al*Bh -------------
template <bool CAUSAL>
static __device__ __forceinline__ void gemm3_core(
        const __bf16* __restrict__ Ah, const __bf16* __restrict__ Al,
        const __bf16* __restrict__ Bh, const __bf16* __restrict__ Bl,
        float* __restrict__ C, int K, int lda, int ldb, int ldc,
        int row_base, int bx, int by) {
    int row0 = by * GBM + row_base, col0 = bx * GBN;
    if (CAUSAL && col0 > row0 + GBM - 1) return;
    __shared__ __bf16 sAh[GBM * GBK], sAl[GBM * GBK];
    __shared__ __bf16 sBh[GBN * GBK], sBl[GBN * GBK];
    int tid = threadIdx.x;
    int lane = tid & 63, wid = tid >> 6;
    int quad = lane >> 4, l16 = lane & 15;
    int wm = wid >> 1, wn = wid & 1;

    f32x4 acc[4][2] = {};
    int am = tid >> 1, ah = tid & 1;
    int bn = tid >> 2, bq = tid & 3;

    for (int k0 = 0; k0 < K; k0 += GBK) {
        size_t aoff = (size_t)(row0 + am) * lda + k0 + ah * 16;
        uint4* dah = (uint4*)&sAh[am * GBK + ah * 16];
        uint4* dal = (uint4*)&sAl[am * GBK + ah * 16];
        dah[0] = ((const uint4*)(Ah + aoff))[0];
        dah[1] = ((const uint4*)(Ah + aoff))[1];
        dal[0] = ((const uint4*)(Al + aoff))[0];
        dal[1] = ((const uint4*)(Al + aoff))[1];
        size_t boff = (size_t)(col0 + bn) * ldb + k0 + bq * 8;
        *(uint4*)&sBh[bn * GBK + bq * 8] = *(const uint4*)(Bh + boff);
        *(uint4*)&sBl[bn * GBK + bq * 8] = *(const uint4*)(Bl + boff);
        __syncthreads();
        bf16x8 afh[4], afl[4], bfh[2], bfl[2];
        #pragma unroll
        for (int mi = 0; mi < 4; ++mi) {
            int o = (wm * 64 + mi * 16 + l16) * GBK + quad * 8;
            afh[mi] = *(const bf16x8*)&sAh[o];
            afl[mi] = *(const bf16x8*)&sAl[o];
        }
        #pragma unroll
        for (int ni = 0; ni < 2; ++ni) {
            int o = (wn * 32 + ni * 16 + l16) * GBK + quad * 8;
            bfh[ni] = *(const bf16x8*)&sBh[o];
            bfl[ni] = *(const bf16x8*)&sBl[o];
        }
        #pragma unroll
        for (int mi = 0; mi < 4; ++mi)
            #pragma unroll
            for (int ni = 0; ni < 2; ++ni) {
                acc[mi][ni] = __builtin_amdgcn_mfma_f32_16x16x32_bf16(
                    afl[mi], bfh[ni], acc[mi][ni], 0, 0, 0);
                acc[mi][ni] = __builtin_amdgcn_mfma_f32_16x16x32_bf16(
                    afh[mi], bfl[ni], acc[mi][ni], 0, 0, 0);
                acc[mi][ni] = __builtin_amdgcn_mfma_f32_16x16x32_bf16(
                    afh[mi], bfh[ni], acc[mi][ni], 0, 0, 0);
            }
        __syncthreads();
    }
    #pragma unroll
    for (int mi = 0; mi < 4; ++mi)
        #pragma unroll
        for (int ni = 0; ni < 2; ++ni)
            #pragma unroll
            for (int r = 0; r < 4; ++r) {
                int row = row0 + wm * 64 + mi * 16 + quad * 4 + r;
                int col = col0 + wn * 32 + ni * 16 + l16;
                C[(size_t)row * ldc + col] = acc[mi][ni][r];
            }
}

// q_lora GEMM with K-split x4 (underfilled otherwise: 192 blocks on 256 CUs)
__global__ __launch_bounds__(256) void gemm3_ks(const __bf16* __restrict__ Ah,
                                                const __bf16* __restrict__ Al,
                                                const __bf16* __restrict__ Bh,
                                                const __bf16* __restrict__ Bl,
                                                float* __restrict__ Cpart,
                                                int Ksub, int lda, int ldb, int ldc,
                                                long sC) {
    int bz = blockIdx.z, koff = bz * Ksub;
    gemm3_core<false>(Ah + koff, Al + koff, Bh + koff, Bl + koff,
                      Cpart + (size_t)bz * sC, Ksub, lda, ldb, ldc, 0,
                      blockIdx.x, blockIdx.y);
}

// ============ fused mid GEMMs: qbuf | kv | iqraw | ikraw (independent) ============
__global__ __launch_bounds__(256) void fused_mid(
        const __bf16* __restrict__ qlH, const __bf16* __restrict__ qlL,
        const __bf16* __restrict__ wq_b_bf, __bf16* __restrict__ qbuf_bf,
        const __bf16* __restrict__ hidH, const __bf16* __restrict__ hidL,
        const __bf16* __restrict__ wkv_a_bf, float* __restrict__ kv,
        const __bf16* __restrict__ iwqH, const __bf16* __restrict__ iwqL,
        float* __restrict__ iqraw,
        const __bf16* __restrict__ iwkH, const __bf16* __restrict__ iwkL,
        float* __restrict__ ikraw) {
    int b = blockIdx.x;
    if (b < 768) {            // qbuf: [2048 x 3072] = ql * wq_b^T, K=768
        gemm_s_core<__bf16>(qlH, wq_b_bf, qbuf_bf, QLORA, QLORA, QLORA,
                            NHEAD * QKHEAD, b % 48, b / 48);
    } else if (b < 912) {     // kv: [2048 x 576] = hid * wkv_a^T, K=2048
        int r = b - 768;
        gemm_s_core<float>(hidH, wkv_a_bf, kv, HIDDEN, HIDDEN, HIDDEN, DLAT,
                           r % 9, r / 9);
    } else if (b < 1168) {    // iqraw: [2048 x 1024] = ql * idx_wq_b^T, K=768 (~f32)
        int r = b - 912;
        gemm3_core<false>(qlH, qlL, iwqH, iwqL, iqraw, QLORA, QLORA, QLORA,
                          HIN * DIN, 0, r & 15, r >> 4);
    } else {                  // ikraw: [2048 x 128] = hid * idx_wk^T, K=2048 (~f32)
        int r = b - 1168;
        gemm3_core<false>(hidH, hidL, iwkH, iwkL, ikraw, HIDDEN, HIDDEN, HIDDEN,
                          DIN, 0, r & 1, r >> 1);
    }
}

// ============ fused stage-2 GEMMs: qeff-nope (batched) | iscore (causal) ============
// qeff-nope: 2048 blocks (8 x 16 x 16 heads). iscore: 384 blocks (32 cols x 12 rows;
// rows 512..2047 only — by MUST stay < 12 or we write past iscore into weights).
__global__ __launch_bounds__(256) void fused2(
        const __bf16* __restrict__ qbuf_bf, const __bf16* __restrict__ wknt,
        __bf16* __restrict__ qeff,
        const __bf16* __restrict__ cqH, const __bf16* __restrict__ cqL,
        const __bf16* __restrict__ ikH, const __bf16* __restrict__ ikL,
        float* __restrict__ iscore) {
    int b = blockIdx.x;
    if (b < 2048) {           // qeff[...,0:512] per head: q_nope * wknt^T, K=128
        int bx = b & 7, by = (b >> 3) & 15, bz = b >> 7;
        gemm_s_core<__bf16>(qbuf_bf + bz * QKHEAD, wknt + (size_t)bz * 512 * 128,
                            qeff + bz * DLAT, 128, NHEAD * QKHEAD, 128,
                            NHEAD * DLAT, bx, by);
    } else {                  // iscore rows 512..2047, lower-triangle blocks, K=128
        int r = b - 2048;     // r in [0, 384)
        gemm3_core<true>(cqH, cqL, ikH, ikL, iscore, DIN, DIN, DIN, S_LEN,
                         TOPKN, r & 31, r >> 5);
    }
}

// ---------------- RMSNorm of 4 K-split partial sums -> split hi/lo bf16 ----------------
__global__ __launch_bounds__(256) void rmsnorm_split4(const float* __restrict__ p,
                                                      long ps,
                                                      const float* __restrict__ w,
                                                      __bf16* __restrict__ yH,
                                                      __bf16* __restrict__ yL, int ncols) {
    int row = blockIdx.x, tid = threadIdx.x;
    const float* p0 = p + (size_t)row * ncols;
    float ss = 0.f;
    for (int c = tid; c < ncols; c += 256) {
        float v = p0[c] + p0[ps + c] + p0[2 * ps + c] + p0[3 * ps + c];
        ss += v * v;
    }
    __shared__ float red[4];
    ss = wave_reduce_sum(ss);
    if ((tid & 63) == 0) red[tid >> 6] = ss;
    __syncthreads();
    float tot = red[0] + red[1] + red[2] + red[3];
    float inv = rsqrtf(tot / (float)ncols + EPSF);
    for (int c = tid; c < ncols; c += 256) {
        float v = p0[c] + p0[ps + c] + p0[2 * ps + c] + p0[3 * ps + c];
        splitw(yH, yL, (size_t)row * ncols + c, v * inv * w[c]);
    }
}

// ===== fused post: rope_qeff | kv_post | ik_post | cq2 — one block per position s =====
__global__ __launch_bounds__(256) void fused_post(
        const __bf16* __restrict__ qbuf, __bf16* __restrict__ qeff,
        const float* __restrict__ kv, const float* __restrict__ kvw,
        __bf16* __restrict__ klat,
        const float* __restrict__ ikraw, const float* __restrict__ lnw,
        const float* __restrict__ lnb, __bf16* __restrict__ ikH, __bf16* __restrict__ ikL,
        const float* __restrict__ iqraw, const float* __restrict__ hid,
        const float* __restrict__ iww, __bf16* __restrict__ cqH, __bf16* __restrict__ cqL,
        const float* __restrict__ cosT, const float* __restrict__ sinT) {
    int s = blockIdx.x, tid = threadIdx.x;
    int lane = tid & 63, wid = tid >> 6;

    // ---- A: rope on q -> qeff[...,512:576] ----
    for (int i = tid; i < NHEAD * 32; i += 256) {
        int h = i >> 5, d = i & 31;
        const __bf16* base = qbuf + (size_t)s * (NHEAD * QKHEAD) + h * QKHEAD + QKNOPE;
        float x1 = (float)base[d], x2 = (float)base[d + 32];
        float c1 = cosT[s * 64 + d],      s1 = sinT[s * 64 + d];
        float c2 = cosT[s * 64 + d + 32], s2 = sinT[s * 64 + d + 32];
        __bf16* o = qeff + (size_t)s * (NHEAD * DLAT) + h * DLAT + 512;
        o[d]      = (__bf16)(x1 * c1 - x2 * s1);
        o[d + 32] = (__bf16)(x2 * c2 + x1 * s2);
    }

    // ---- B: kv rmsnorm 512 + rope 64 -> klat ----
    {
        const float* row = kv + (size_t)s * DLAT;
        float ss = 0.f;
        for (int c = tid; c < KVLORA; c += 256) { float v = row[c]; ss += v * v; }
        __shared__ float redB[4];
        ss = wave_reduce_sum(ss);
        if (lane == 0) redB[wid] = ss;
        __syncthreads();
        float tot = redB[0] + redB[1] + redB[2] + redB[3];
        float inv = rsqrtf(tot / (float)KVLORA + EPSF);
        __bf16* orow = klat + (size_t)s * DLAT;
        for (int c = tid; c < KVLORA; c += 256)
            orow[c] = (__bf16)(row[c] * inv * kvw[c]);
        if (tid < 32) {
            int d = tid;
            float x1 = row[KVLORA + d], x2 = row[KVLORA + d + 32];
            float c1 = cosT[s * 64 + d],      s1 = sinT[s * 64 + d];
            float c2 = cosT[s * 64 + d + 32], s2 = sinT[s * 64 + d + 32];
            orow[512 + d]      = (__bf16)(x1 * c1 - x2 * s1);
            orow[512 + d + 32] = (__bf16)(x2 * c2 + x1 * s2);
        }
    }

    // ---- C: ik layer_norm(128) + rope -> split ----
    {
        float x = (tid < DIN) ? ikraw[(size_t)s * DIN + tid] : 0.f;
        __shared__ float redC1[4], redC2[4], sy[DIN];
        float sm = wave_reduce_sum(x);
        if (lane == 0) redC1[wid] = sm;
        __syncthreads();
        float mean = (redC1[0] + redC1[1] + redC1[2] + redC1[3]) / (float)DIN;
        float dx = (tid < DIN) ? (x - mean) : 0.f;
        float vs = wave_reduce_sum(dx * dx);
        if (lane == 0) redC2[wid] = vs;
        __syncthreads();
        float var = (redC2[0] + redC2[1] + redC2[2] + redC2[3]) / (float)DIN;
        if (tid < DIN) sy[tid] = dx * rsqrtf(var + EPSF) * lnw[tid] + lnb[tid];
        __syncthreads();
        size_t ro = (size_t)s * DIN;
        if (tid < 32) {
            int d = tid;
            float c1 = cosT[s * 64 + d],      s1 = sinT[s * 64 + d];
            float c2 = cosT[s * 64 + d + 32], s2 = sinT[s * 64 + d + 32];
            splitw(ikH, ikL, ro + d,      sy[d] * c1 - sy[d + 32] * s1);
            splitw(ikH, ikL, ro + d + 32, sy[d + 32] * c2 + sy[d] * s2);
        } else if (tid >= 64 && tid < DIN) {
            splitw(ikH, ikL, ro + tid, sy[tid]);
        }
        __syncthreads();
    }

    // ---- D: iw dots + fold into roped iq -> cq split ----
    {
        __shared__ float redD[4][HIN], siw[HIN];
        float a8[HIN] = {};
        const float* xr = hid + (size_t)s * HIDDEN;
        for (int c = tid; c < HIDDEN; c += 256) {
            float x = xr[c];
            #pragma unroll
            for (int h = 0; h < HIN; ++h) a8[h] += x * iww[h * HIDDEN + c];
        }
        #pragma unroll
        for (int h = 0; h < HIN; ++h) a8[h] = wave_reduce_sum(a8[h]);
        if (lane == 0)
            #pragma unroll
            for (int h = 0; h < HIN; ++h) redD[wid][h] = a8[h];
        __syncthreads();
        if (tid < HIN)
            siw[tid] = redD[0][tid] + redD[1][tid] + redD[2][tid] + redD[3][tid];
        __syncthreads();
        if (tid < DIN) {
            int d = tid;
            float acc = 0.f;
            float c1 = 0.f, s1 = 0.f;
            if (d < 64) { c1 = cosT[s * 64 + d]; s1 = sinT[s * 64 + d]; }
            #pragma unroll
            for (int h = 0; h < HIN; ++h) {
                const float* base = iqraw + ((size_t)s * HIN + h) * DIN;
                float v;
                if (d < 32)       v = base[d] * c1 - base[d + 32] * s1;
                else if (d < 64)  v = base[d] * c1 + base[d - 32] * s1;
                else              v = base[d];
                acc += siw[h] * v;
            }
            splitw(cqH, cqL, (size_t)s * DIN + d, acc * 0.03125f);
        }
    }
}

// ------------- exact top-512 per row (rows q >= 512), parallel radix select -------------
__global__ __launch_bounds__(256) void topk_rows(const float* __restrict__ iscore,
                                                 int* __restrict__ topk) {
    int q = TOPKN + blockIdx.x;
    int n = q + 1;
    __shared__ uint32_t skey[S_LEN];
    __shared__ int hist[256];
    __shared__ int scan[256];
    __shared__ uint32_t sp;
    __shared__ int sr, pos;
    int tid = threadIdx.x;
    const float* row = iscore + (size_t)q * S_LEN;
    for (int i = tid; i < n; i += 256) {
        uint32_t u = __float_as_uint(row[i]);
        skey[i] = (u & 0x80000000u) ? ~u : (u | 0x80000000u);
    }
    __syncthreads();
    uint32_t prefix = 0;
    int remk = TOPKN;
    for (int pass = 0; pass < 4; ++pass) {
        int shift = 24 - 8 * pass;
        uint32_t pmask = pass ? (0xFFFFFFFFu << (shift + 8)) : 0u;
        hist[tid] = 0;
        __syncthreads();
        for (int i = tid; i < n; i += 256) {
            uint32_t u = skey[i];
            if ((u & pmask) == prefix) atomicAdd(&hist[(u >> shift) & 255], 1);
        }
        __syncthreads();
        scan[tid] = hist[tid];
        __syncthreads();
        for (int step = 1; step < 256; step <<= 1) {
            int v = (tid + step < 256) ? scan[tid + step] : 0;
            __syncthreads();
            scan[tid] += v;
            __syncthreads();
        }
        int Sb = scan[tid];
        int Snext = (tid < 255) ? scan[tid + 1] : 0;
        if (Sb >= remk && Snext < remk) {
            sp = prefix | ((uint32_t)tid << shift);
            sr = remk - Snext;
        }
        __syncthreads();
        prefix = sp; remk = sr;
        __syncthreads();
    }
    if (tid == 0) pos = 0;
    __syncthreads();
    int* orow = topk + (size_t)q * TOPKN;
    for (int i = tid; i < n; i += 256) {
        if (skey[i] > prefix) { int p = atomicAdd(&pos, 1); orow[p] = i; }
    }
    __syncthreads();
    int base = pos;
    int chunk = (n + 255) >> 8;
    int lo = tid * chunk, hiEnd = lo + chunk;
    if (hiEnd > n) hiEnd = n;
    int cnt = 0;
    for (int i = lo; i < hiEnd; ++i) cnt += (skey[i] == prefix);
    scan[tid] = cnt;
    __syncthreads();
    for (int step = 1; step < 256; step <<= 1) {
        int v = (tid >= step) ? scan[tid - step] : 0;
        __syncthreads();
        scan[tid] += v;
        __syncthreads();
    }
    int r = scan[tid] - cnt;
    for (int i = lo; i < hiEnd && r < remk; ++i) {
        if (skey[i] == prefix) { orow[base + r] = i; ++r; }
    }
}

// ---------------- absorbed-MLA flash attention: one workgroup per q --------------
#define SKS 584   // shorts per sK row (1168 B)
__global__ __launch_bounds__(256) void attn2(const __bf16* __restrict__ qeff,
                                             const __bf16* __restrict__ klat,
                                             const int* __restrict__ topk,
                                             __bf16* __restrict__ o_lat) {
    int q = (blockIdx.x * 997) & (S_LEN - 1);   // spread light causal rows across tail
    int tid = threadIdx.x;
    int lane = tid & 63, wid = tid >> 6;
    int l16 = lane & 15, quad = lane >> 4;
    int wn = wid & 1, wk = wid >> 1;

    __shared__ short sK[32 * SKS];
    __shared__ float s_part[2][16][37];
    __shared__ float s_S[16][38];
    __shared__ float s_m[16], s_l[16], s_alpha[16], s_inv[16];

    int L = (q < TOPKN) ? (q + 1) : TOPKN;
    int nt = (L + 31) >> 5;
    const int* idxr = topk + (size_t)q * TOPKN;

    bf16x8 qf[9];
    const __bf16* qrow = qeff + (size_t)q * (NHEAD * DLAT) + l16 * DLAT + wk * 288 + quad * 8;
    #pragma unroll
    for (int s = 0; s < 9; ++s) qf[s] = *(const bf16x8*)(qrow + s * 32);

    if (tid < 16) { s_m[tid] = -1e30f; s_l[tid] = 0.f; }

    f32x4 oacc[8];
    #pragma unroll
    for (int i = 0; i < 8; ++i) oacc[i] = (f32x4){0.f, 0.f, 0.f, 0.f};

    int srow = tid >> 3, schk = tid & 7;

    for (int t = 0; t < nt; ++t) {
        int ki = t * 32 + srow;
        int gk = 0;
        if (ki < L) gk = (q < TOPKN) ? ki : idxr[ki];
        const uint4* src = (const uint4*)(klat + (size_t)gk * DLAT) + schk * 9;
        uint4* dst = (uint4*)((char*)sK + srow * (SKS * 2) + schk * 144);
        #pragma unroll
        for (int c = 0; c < 9; ++c) dst[c] = src[c];
        __syncthreads();

        f32x4 sacc = {0.f, 0.f, 0.f, 0.f};
        const short* kbase = sK + (wn * 16 + l16) * SKS + wk * 288 + quad * 8;
        #pragma unroll
        for (int s = 0; s < 9; ++s) {
            bf16x8 kf = *(const bf16x8*)(kbase + s * 32);
            sacc = __builtin_amdgcn_mfma_f32_16x16x32_bf16(qf[s], kf, sacc, 0, 0, 0);
        }
        #pragma unroll
        for (int r = 0; r < 4; ++r)
            s_part[wk][quad * 4 + r][wn * 16 + l16] = sacc[r];
        __syncthreads();

        {
            int h = tid >> 4, k0 = (tid & 15) * 2;
            float v0 = -1e30f, v1 = -1e30f;
            if (t * 32 + k0 < L)
                v0 = (s_part[0][h][k0] + s_part[1][h][k0]) * SCALE_ATT;
            if (t * 32 + k0 + 1 < L)
                v1 = (s_part[0][h][k0 + 1] + s_part[1][h][k0 + 1]) * SCALE_ATT;
            float mt = fmaxf(v0, v1);
            #pragma unroll
            for (int o = 1; o < 16; o <<= 1) mt = fmaxf(mt, __shfl_xor(mt, o));
            float mold = s_m[h];
            float mnew = fmaxf(mold, mt);
            float p0 = __expf(v0 - mnew), p1 = __expf(v1 - mnew);
            float ls = p0 + p1;
            #pragma unroll
            for (int o = 1; o < 16; o <<= 1) ls += __shfl_xor(ls, o);
            *(float2*)&s_S[h][k0] = make_float2(p0, p1);
            if ((tid & 15) == 0) {
                float alpha = __expf(mold - mnew);
                s_alpha[h] = alpha;
                s_m[h] = mnew;
                s_l[h] = s_l[h] * alpha + ls;
            }
        }
        __syncthreads();

        f32x4 al4 = *(const f32x4*)&s_alpha[quad * 4];
        // P A-frag, k-slot permutation j -> j^quad, loaded as 4 aligned b64s
        bf16x8 pf;
        int qhi = quad & 2, qlo = quad & 1;
        #pragma unroll
        for (int p = 0; p < 4; ++p) {
            float2 v = *(const float2*)&s_S[l16][quad * 8 + ((2 * p) ^ qhi)];
            float e0 = qlo ? v.y : v.x, e1 = qlo ? v.x : v.y;
            pf[2 * p]     = (__bf16)e0;
            pf[2 * p + 1] = (__bf16)e1;
        }
        const __bf16* sKb = (const __bf16*)sK;
        #pragma unroll
        for (int n = 0; n < 8; ++n) {
            int dim = wid * 128 + n * 16 + l16;
            bf16x8 vf;
            #pragma unroll
            for (int j = 0; j < 8; ++j)
                vf[j] = sKb[(quad * 8 + (j ^ quad)) * SKS + dim];
            #pragma unroll
            for (int r = 0; r < 4; ++r) oacc[n][r] *= al4[r];
            oacc[n] = __builtin_amdgcn_mfma_f32_16x16x32_bf16(pf, vf, oacc[n], 0, 0, 0);
        }
        __syncthreads();
    }

    if (tid < 16) s_inv[tid] = 1.f / s_l[tid];
    __syncthreads();
    f32x4 inv4 = *(const f32x4*)&s_inv[quad * 4];
    #pragma unroll
    for (int n = 0; n < 8; ++n) {
        int dim = wid * 128 + n * 16 + l16;
        #pragma unroll
        for (int r = 0; r < 4; ++r) {
            int h = quad * 4 + r;
            o_lat[(size_t)q * 8192 + h * 512 + dim] = (__bf16)(oacc[n][r] * inv4[r]);
        }
    }
}

extern "C" void kernel_launch(void* const* d_in, const int* in_sizes, int n_in,
                              void* d_out, int out_size, void* d_ws, size_t ws_size,
                              hipStream_t stream) {
    const float* hid          = (const float*)d_in[0];
    const float* cosT         = (const float*)d_in[1];
    const float* sinT         = (const float*)d_in[2];
    const float* wq_a         = (const float*)d_in[3];
    const float* q_a_norm_w   = (const float*)d_in[4];
    const float* wq_b         = (const float*)d_in[5];
    const float* wkv_a        = (const float*)d_in[6];
    const float* kv_a_norm_w  = (const float*)d_in[7];
    const float* wkv_b        = (const float*)d_in[8];
    const float* wo           = (const float*)d_in[9];
    const float* idx_wq_b     = (const float*)d_in[10];
    const float* idx_wk       = (const float*)d_in[11];
    const float* idx_k_norm_w = (const float*)d_in[12];
    const float* idx_k_norm_b = (const float*)d_in[13];
    const float* idx_weights_w= (const float*)d_in[14];
    float* out = (float*)d_out;

    char* ws = (char*)d_ws;
    size_t off = 0;
    auto alloc = [&](size_t nbytes) {
        void* p = (void*)(ws + off);
        off += (nbytes + 255) & ~(size_t)255;
        return p;
    };
    __bf16* qbuf_bf  = (__bf16*)alloc((size_t)S_LEN * NHEAD * QKHEAD * 2);
    float*  kv       = (float*) alloc((size_t)S_LEN * DLAT * 4);
    __bf16* klat_bf  = (__bf16*)alloc((size_t)S_LEN * DLAT * 2);
    __bf16* qeff_bf  = (__bf16*)alloc((size_t)S_LEN * NHEAD * DLAT * 2);
    int*    topk     = (int*)   alloc((size_t)S_LEN * TOPKN * 4);
    // union B: [hidH | wkv_a_bf] (early) / attn_o_bf (late)
    char* uB = (char*)alloc((size_t)S_LEN * HIDDEN * 2 + (size_t)DLAT * HIDDEN * 2);
    __bf16* hidH      = (__bf16*)uB;
    __bf16* wkv_a_bf  = (__bf16*)(uB + (size_t)S_LEN * HIDDEN * 2);
    __bf16* attn_o_bf = (__bf16*)uB;
    __bf16* hidL      = (__bf16*)alloc((size_t)S_LEN * HIDDEN * 2);
    // union C: qpart (earliest, 25.2MB) / indexer block (early) / o_lat (late, 33.6MB)
    char* uC = (char*)alloc((size_t)S_LEN * NHEAD * 512 * 2);
    float*  qpart    = (float*)uC;               // 4 x [2048 x 768] K-split partials
    __bf16* o_lat_bf = (__bf16*)uC;
    float* iqraw  = (float*)uC;
    float* ikraw  = (float*)(uC + 8388608);
    float* iscore = (float*)(uC + 11599872);
    __bf16* wq_b_bf  = (__bf16*)alloc((size_t)(NHEAD * QKHEAD) * QLORA * 2);
    __bf16* wkv_b_bf = (__bf16*)alloc((size_t)(NHEAD * 256) * KVLORA * 2);
    __bf16* wknt_bf  = (__bf16*)alloc((size_t)NHEAD * 512 * 128 * 2);
    __bf16* wo_bf    = (__bf16*)alloc((size_t)HIDDEN * (NHEAD * VDIM) * 2);
    __bf16* wqaH = (__bf16*)alloc((size_t)QLORA * HIDDEN * 2);
    __bf16* wqaL = (__bf16*)alloc((size_t)QLORA * HIDDEN * 2);
    __bf16* qlH  = (__bf16*)alloc((size_t)S_LEN * QLORA * 2);
    __bf16* qlL  = (__bf16*)alloc((size_t)S_LEN * QLORA * 2);
    __bf16* iwqH = (__bf16*)alloc((size_t)(HIN * DIN) * QLORA * 2);
    __bf16* iwqL = (__bf16*)alloc((size_t)(HIN * DIN) * QLORA * 2);
    __bf16* iwkH = (__bf16*)alloc((size_t)DIN * HIDDEN * 2);
    __bf16* iwkL = (__bf16*)alloc((size_t)DIN * HIDDEN * 2);
    __bf16* ikH  = (__bf16*)alloc((size_t)S_LEN * DIN * 2);
    __bf16* ikL  = (__bf16*)alloc((size_t)S_LEN * DIN * 2);
    __bf16* cqH  = (__bf16*)alloc((size_t)S_LEN * DIN * 2);
    __bf16* cqL  = (__bf16*)alloc((size_t)S_LEN * DIN * 2);
    (void)ws_size; (void)in_sizes; (void)n_in; (void)out_size;

    dim3 blk(256);

    // 1. all casts / splits / transpose in one launch
    prep_all<<<PREP_BLOCKS, blk, 0, stream>>>(
        hid, hidH, hidL, wq_a, wqaH, wqaL, idx_wq_b, iwqH, iwqL,
        idx_wk, iwkH, iwkL, wq_b, wq_b_bf, wkv_a, wkv_a_bf,
        wkv_b, wkv_b_bf, wo, wo_bf, wknt_bf);

    // 2. q_lora (~f32, K-split x4 for occupancy) + rmsnorm(sum of partials)
    gemm3_ks<<<dim3(QLORA / GBN, S_LEN / GBM, 4), blk, 0, stream>>>(
        hidH, hidL, wqaH, wqaL, qpart, HIDDEN / 4, HIDDEN, HIDDEN, QLORA,
        (long)S_LEN * QLORA);
    rmsnorm_split4<<<S_LEN, 256, 0, stream>>>(qpart, (long)S_LEN * QLORA,
                                              q_a_norm_w, qlH, qlL, QLORA);

    // 3. four independent GEMMs in one launch: qbuf | kv | iqraw | ikraw
    fused_mid<<<1200, blk, 0, stream>>>(qlH, qlL, wq_b_bf, qbuf_bf,
                                        hidH, hidL, wkv_a_bf, kv,
                                        iwqH, iwqL, iqraw, iwkH, iwkL, ikraw);

    // 4. all elementwise post-processing in one launch
    fused_post<<<S_LEN, 256, 0, stream>>>(qbuf_bf, qeff_bf, kv, kv_a_norm_w, klat_bf,
                                          ikraw, idx_k_norm_w, idx_k_norm_b, ikH, ikL,
                                          iqraw, hid, idx_weights_w, cqH, cqL,
                                          cosT, sinT);

    // 5. qeff-nope (2048 blocks) + iscore causal (384 blocks) in one launch
    fused2<<<2048 + 384, blk, 0, stream>>>(qbuf_bf, wknt_bf, qeff_bf,
                                           cqH, cqL, ikH, ikL, iscore);

    // 6. exact top-512
    topk_rows<<<S_LEN - TOPKN, 256, 0, stream>>>(iscore, topk);

    // 7. absorbed attention -> o_lat
    attn2<<<S_LEN, 256, 0, stream>>>(qeff_bf, klat_bf, topk, o_lat_bf);

    // 8. V projection per head, then output projection
    gemm_s<__bf16><<<dim3(VDIM / GBN, S_LEN / GBM, NHEAD), blk, 0, stream>>>(
        o_lat_bf, wkv_b_bf + 128 * 512, attn_o_bf, 512,
        NHEAD * 512, 512, NHEAD * VDIM, 512, 256 * 512, VDIM);
    gemm_s<float><<<dim3(HIDDEN / GBN, S_LEN / GBM, 1), blk, 0, stream>>>(
        attn_o_bf, wo_bf, out, NHEAD * VDIM,
        NHEAD * VDIM, NHEAD * VDIM, HIDDEN, 0, 0, 0);
}